// Round 3
// baseline (2045.677 us; speedup 1.0000x reference)
//
#include <hip/hip_runtime.h>
#include <hip/hip_bf16.h>
#include <cstdint>
#include <cstddef>

typedef __bf16 bf16;
typedef __attribute__((ext_vector_type(8))) __bf16 bf16x8;
typedef __attribute__((ext_vector_type(4))) __bf16 bf16x4;
typedef __attribute__((ext_vector_type(4))) float f32x4;

__device__ __forceinline__ f32x4 mfma16(bf16x8 a, bf16x8 b, f32x4 c) {
    return __builtin_amdgcn_mfma_f32_16x16x32_bf16(a, b, c, 0, 0, 0);
}

__device__ __forceinline__ void async_copy16(const void* g, void* l) {
    __builtin_amdgcn_global_load_lds((const __attribute__((address_space(1))) void*)g,
                                     (__attribute__((address_space(3))) void*)l,
                                     16, 0, 0);
}

// ---------------- embedding ----------------
__global__ __launch_bounds__(256)
void embed_kernel(const int* __restrict__ ids, const float* __restrict__ te,
                  const float* __restrict__ pe, float* __restrict__ x)
{
    const int row = blockIdx.x;
    const int s = row & 1023;
    const int id = ids[row];
    const f32x4* a = (const f32x4*)(te + (size_t)id * 1024);
    const f32x4* b = (const f32x4*)(pe + (size_t)s * 1024);
    f32x4* o = (f32x4*)(x + (size_t)row * 1024);
    o[threadIdx.x] = a[threadIdx.x] + b[threadIdx.x];
}

// ---------------- layernorm ----------------
__global__ __launch_bounds__(256)
void ln_kernel(const float* __restrict__ x, const float* __restrict__ sc,
               const float* __restrict__ bi, bf16* __restrict__ out)
{
    const int row = blockIdx.x, t = threadIdx.x;
    const f32x4 v = ((const f32x4*)(x + (size_t)row * 1024))[t];
    float s = v[0] + v[1] + v[2] + v[3];
    float q = v[0]*v[0] + v[1]*v[1] + v[2]*v[2] + v[3]*v[3];
    #pragma unroll
    for (int o = 1; o < 64; o <<= 1) { s += __shfl_xor(s, o); q += __shfl_xor(q, o); }
    __shared__ float red[8];
    const int wv = t >> 6, lane = t & 63;
    if (lane == 0) { red[wv] = s; red[4 + wv] = q; }
    __syncthreads();
    s = red[0] + red[1] + red[2] + red[3];
    q = red[4] + red[5] + red[6] + red[7];
    const float mean = s * (1.f / 1024.f);
    const float var  = q * (1.f / 1024.f) - mean * mean;
    const float rstd = rsqrtf(var + 1e-5f);
    const f32x4 scv = ((const f32x4*)sc)[t];
    const f32x4 biv = ((const f32x4*)bi)[t];
    bf16x4 o4;
    #pragma unroll
    for (int j = 0; j < 4; j++) o4[j] = (bf16)((v[j] - mean) * rstd * scv[j] + biv[j]);
    *(bf16x4*)(out + (size_t)row * 1024 + t * 4) = o4;
}

// ---------------- weight transpose+convert ----------------
__global__ __launch_bounds__(256)
void wcvt_kernel(const float* __restrict__ W, bf16* __restrict__ BT, int K, int N)
{
    __shared__ float tile[64][65];
    const int n0 = blockIdx.x << 6, k0 = blockIdx.y << 6;
    const int tx = threadIdx.x & 15, ty = threadIdx.x >> 4;
    #pragma unroll
    for (int r = 0; r < 4; r++) {
        const f32x4 v = *(const f32x4*)&W[(size_t)(k0 + ty + r*16) * N + n0 + tx*4];
        tile[ty + r*16][tx*4 + 0] = v[0];
        tile[ty + r*16][tx*4 + 1] = v[1];
        tile[ty + r*16][tx*4 + 2] = v[2];
        tile[ty + r*16][tx*4 + 3] = v[3];
    }
    __syncthreads();
    #pragma unroll
    for (int r = 0; r < 4; r++) {
        const int n = ty + r*16;
        bf16x4 o;
        #pragma unroll
        for (int j = 0; j < 4; j++) o[j] = (bf16)tile[tx*4 + j][n];
        *(bf16x4*)&BT[(size_t)(n0 + n) * K + k0 + tx*4] = o;
    }
}

// ---------------- 128-tile GEMM (2-barrier structure) for small-N GEMMs ----------------
template<int BM, int BN, int EPI>
__global__ __launch_bounds__(256)
void gemm_kernel(const bf16* __restrict__ A, const bf16* __restrict__ BT,
                 const float* __restrict__ bias, float* __restrict__ resid,
                 bf16* __restrict__ outb, float* __restrict__ outf,
                 int N, int K)
{
    constexpr int MT = 2048 / BM;
    constexpr int WM = BM / 2, WN = BN / 2;
    constexpr int FM = WM / 16, FN = WN / 16;
    constexpr int CA = BM / 32, CB = BN / 32;
    __shared__ __align__(16) bf16 Asmem[BM * 64];
    __shared__ __align__(16) bf16 Bsmem[BN * 64];

    const int nwg = gridDim.x;
    const int q = nwg >> 3, rr = nwg & 7;
    const int xcd = blockIdx.x & 7, ix = blockIdx.x >> 3;
    const int nid = (xcd < rr ? xcd * (q + 1) : rr * (q + 1) + (xcd - rr) * q) + ix;
    const int bm = nid % MT, bn = nid / MT;

    const int tid = threadIdx.x;
    const int lane = tid & 63, wave = tid >> 6;
    const int wr = wave >> 1, wc = wave & 1;
    f32x4 acc[FM][FN];
    #pragma unroll
    for (int m = 0; m < FM; m++)
        #pragma unroll
        for (int n = 0; n < FN; n++) acc[m][n] = f32x4{0.f, 0.f, 0.f, 0.f};

    const bf16* Abase = A  + (size_t)bm * BM * K;
    const bf16* Bbase = BT + (size_t)bn * BN * K;
    const int K64 = K >> 6;
    for (int kt = 0; kt < K64; kt++) {
        __syncthreads();
        #pragma unroll
        for (int p = 0; p < CA; p++) {
            const int idx = p * 256 + tid;
            const int r = idx >> 3, c = (idx & 7) << 3;
            async_copy16(Abase + (size_t)r * K + kt * 64 + c, Asmem + idx * 8);
        }
        #pragma unroll
        for (int p = 0; p < CB; p++) {
            const int idx = p * 256 + tid;
            const int r = idx >> 3, c = (idx & 7) << 3;
            async_copy16(Bbase + (size_t)r * K + kt * 64 + c, Bsmem + idx * 8);
        }
        __syncthreads();
        #pragma unroll
        for (int ks = 0; ks < 2; ks++) {
            bf16x8 af[FM], bfv[FN];
            const int ko = ks * 32 + ((lane >> 4) << 3);
            const int ar = wr * WM + (lane & 15);
            const int br = wc * WN + (lane & 15);
            #pragma unroll
            for (int m = 0; m < FM; m++) af[m]  = *(const bf16x8*)&Asmem[(ar + m*16) * 64 + ko];
            #pragma unroll
            for (int n = 0; n < FN; n++) bfv[n] = *(const bf16x8*)&Bsmem[(br + n*16) * 64 + ko];
            #pragma unroll
            for (int m = 0; m < FM; m++)
                #pragma unroll
                for (int n = 0; n < FN; n++)
                    acc[m][n] = mfma16(af[m], bfv[n], acc[m][n]);
        }
    }
    const int r0 = bm * BM + wr * WM + ((lane >> 4) << 2);
    const int c0 = bn * BN + wc * WN + (lane & 15);
    #pragma unroll
    for (int n = 0; n < FN; n++) {
        const int col = c0 + n * 16;
        const float bv = (EPI == 3) ? 0.f : bias[col];
        #pragma unroll
        for (int m = 0; m < FM; m++) {
            const int row = r0 + m * 16;
            const f32x4 a = acc[m][n];
            #pragma unroll
            for (int i = 0; i < 4; i++) {
                const float v = a[i] + bv;
                const size_t off = (size_t)(row + i) * N + col;
                if constexpr (EPI == 0) outb[off] = (bf16)v;
                else if constexpr (EPI == 1) resid[off] += v;
                else if constexpr (EPI == 2) {
                    const float g = 0.5f * v * (1.f + erff(v * 0.70710678118f));
                    outb[off] = (bf16)g;
                } else outf[off] = v;
            }
        }
    }
}

// ---------------- 256x256 8-phase GEMM (T2+T3+T4+T5), M=2048, K mult of 128 ----------------
// EPI: 2 = bias+gelu->bf16 ; 3 = plain f32 (no bias)
// LDS 128 KiB dynamic: A[2buf][2kh][256 rows][32 cols] then B same. Half-tile = 16 KB.
// Swizzle: 16B chunk index within row XOR'd with (row&3), applied on BOTH the
// pre-swizzled global source of global_load_lds and the ds_read address (involution).
// Schedule per K-tile t (buf b=t&1): 4 phases; stage tile t+1's half-tiles one per
// phase (A0,B0,A1,B1); s_waitcnt vmcnt(4) at end of phases 2 and 4 (counted, never 0
// mid-loop); raw s_barrier only (no vmcnt(0) drain); setprio around MFMA quads.
template<int EPI>
__global__ __launch_bounds__(512, 2)
void gemm256_kernel(const bf16* __restrict__ A, const bf16* __restrict__ BT,
                    const float* __restrict__ bias,
                    bf16* __restrict__ outb, float* __restrict__ outf,
                    int N, int K)
{
    extern __shared__ __align__(16) char smem_raw[];
    bf16* smem = (bf16*)smem_raw;

    const int nwg = gridDim.x;
    const int q = nwg >> 3, rr = nwg & 7;
    const int xcd = blockIdx.x & 7, ix = blockIdx.x >> 3;
    const int nid = (xcd < rr ? xcd * (q + 1) : rr * (q + 1) + (xcd - rr) * q) + ix;
    const int bm = nid & 7, bn = nid >> 3;    // M fastest: 8 m-tiles of 256

    const int tid = threadIdx.x, lane = tid & 63, wave = tid >> 6;
    const int wr = wave >> 2, wc = wave & 3;  // 2 M-waves x 4 N-waves, 128x64 per wave

    f32x4 acc[8][4];
    #pragma unroll
    for (int m = 0; m < 8; m++)
        #pragma unroll
        for (int n = 0; n < 4; n++) acc[m][n] = f32x4{0.f, 0.f, 0.f, 0.f};

    const bf16* Abase = A  + (size_t)bm * 256 * K;
    const bf16* Bbase = BT + (size_t)bn * 256 * K;
    const int T = K >> 6;

    // staging: half-tile = 1024 chunks of 16B; thread covers chunks tid and tid+512
    const int c0_ = tid, c1_ = 512 + tid;
    const int r0s = c0_ >> 2, k0s = (((c0_ & 3) ^ (r0s & 3)) << 3);
    const int r1s = c1_ >> 2, k1s = (((c1_ & 3) ^ (r1s & 3)) << 3);

    // ds_read: row = (wave half)*... + lane&15; swizzled chunk is lane-constant
    const int swz = (((lane >> 4) ^ (lane & 3)) << 3);
    const int arow = wr * 128 + (lane & 15);
    const int brow = wc * 64 + (lane & 15);

#define ABLK(b_, kh) ((((b_)*2 + (kh)) << 13))
#define BBLK(b_, kh) (32768 + (((b_)*2 + (kh)) << 13))
#define STAGE_A(t_, kh) { const int b_ = (t_) & 1; \
    async_copy16(Abase + (size_t)r0s * K + (t_)*64 + (kh)*32 + k0s, &smem[ABLK(b_,kh) + c0_*8]); \
    async_copy16(Abase + (size_t)r1s * K + (t_)*64 + (kh)*32 + k1s, &smem[ABLK(b_,kh) + c1_*8]); }
#define STAGE_B(t_, kh) { const int b_ = (t_) & 1; \
    async_copy16(Bbase + (size_t)r0s * K + (t_)*64 + (kh)*32 + k0s, &smem[BBLK(b_,kh) + c0_*8]); \
    async_copy16(Bbase + (size_t)r1s * K + (t_)*64 + (kh)*32 + k1s, &smem[BBLK(b_,kh) + c1_*8]); }
#define LOAD_B(b_, kh) { _Pragma("unroll") for (int n = 0; n < 4; n++) \
    bfv[n] = *(const bf16x8*)&smem[BBLK(b_,kh) + (brow + n*16)*32 + swz]; }
#define LOAD_A(b_, kh, mh) { _Pragma("unroll") for (int m = 0; m < 4; m++) \
    af[m] = *(const bf16x8*)&smem[ABLK(b_,kh) + (arow + ((mh)*4 + m)*16)*32 + swz]; }
#define QUAD(mh) { __builtin_amdgcn_s_setprio(1); \
    _Pragma("unroll") for (int m = 0; m < 4; m++) \
      _Pragma("unroll") for (int n = 0; n < 4; n++) \
        acc[(mh)*4 + m][n] = mfma16(af[m], bfv[n], acc[(mh)*4 + m][n]); \
    __builtin_amdgcn_s_setprio(0); }

    // prologue: stage tile 0 fully; wait for kh0 halves (kh1 stays in flight)
    STAGE_A(0, 0); STAGE_B(0, 0); STAGE_A(0, 1); STAGE_B(0, 1);
    asm volatile("s_waitcnt vmcnt(4)" ::: "memory");
    __builtin_amdgcn_s_barrier();

    for (int t = 0; t < T; t++) {
        const int b = t & 1;
        const bool more = (t + 1) < T;
        bf16x8 af[4], bfv[4];
        // ---- phase 1: kh0, m0-3 ----
        LOAD_B(b, 0); LOAD_A(b, 0, 0);
        if (more) STAGE_A(t + 1, 0);
        __builtin_amdgcn_s_barrier();
        QUAD(0);
        __builtin_amdgcn_s_barrier();
        // ---- phase 2: kh0, m4-7 ----
        LOAD_A(b, 0, 1);
        if (more) STAGE_B(t + 1, 0);
        __builtin_amdgcn_s_barrier();
        QUAD(1);
        if (more) { asm volatile("s_waitcnt vmcnt(4)" ::: "memory"); }
        else      { asm volatile("s_waitcnt vmcnt(0)" ::: "memory"); }
        __builtin_amdgcn_s_barrier();
        // ---- phase 3: kh1, m0-3 ----
        LOAD_B(b, 1); LOAD_A(b, 1, 0);
        if (more) STAGE_A(t + 1, 1);
        __builtin_amdgcn_s_barrier();
        QUAD(0);
        __builtin_amdgcn_s_barrier();
        // ---- phase 4: kh1, m4-7 ----
        LOAD_A(b, 1, 1);
        if (more) STAGE_B(t + 1, 1);
        __builtin_amdgcn_s_barrier();
        QUAD(1);
        if (more) { asm volatile("s_waitcnt vmcnt(4)" ::: "memory"); }
        else      { asm volatile("s_waitcnt vmcnt(0)" ::: "memory"); }
        __builtin_amdgcn_s_barrier();
    }

    // epilogue: D row = (lane>>4)*4+i, col = lane&15
    const int er = bm * 256 + wr * 128 + ((lane >> 4) << 2);
    const int ec = bn * 256 + wc * 64 + (lane & 15);
    #pragma unroll
    for (int n = 0; n < 4; n++) {
        const int col = ec + n * 16;
        const float bv = (EPI == 3) ? 0.f : bias[col];
        #pragma unroll
        for (int m = 0; m < 8; m++) {
            #pragma unroll
            for (int i = 0; i < 4; i++) {
                const float v = acc[m][n][i] + bv;
                const size_t off = (size_t)(er + m * 16 + i) * N + col;
                if constexpr (EPI == 2) {
                    outb[off] = (bf16)(0.5f * v * (1.f + erff(v * 0.70710678118f)));
                } else {
                    outf[off] = v;
                }
            }
        }
    }
#undef ABLK
#undef BBLK
#undef STAGE_A
#undef STAGE_B
#undef LOAD_A
#undef LOAD_B
#undef QUAD
}

// ---------------- fused non-causal attention (flash-style) ----------------
__global__ __launch_bounds__(256)
void attn_kernel(const bf16* __restrict__ qkv, bf16* __restrict__ attno)
{
    __shared__ __align__(16) bf16 Vt[64][136];
    __shared__ __align__(16) bf16 Plds[4][16][40];
    const int b = blockIdx.x >> 4, h = blockIdx.x & 15;
    const int qb = blockIdx.y;
    const int tid = threadIdx.x, lane = tid & 63, wave = tid >> 6;
    const bf16* base = qkv + (size_t)b * 1024 * 3072;
    const int qrow0 = qb * 64 + wave * 16;

    bf16x8 aQ[2];
    {
        const int qr = qrow0 + (lane & 15);
        const bf16* qp = base + (size_t)qr * 3072 + h * 64 + ((lane >> 4) << 3);
        aQ[0] = *(const bf16x8*)qp;
        aQ[1] = *(const bf16x8*)(qp + 32);
    }
    float m_i[4] = {-1e30f, -1e30f, -1e30f, -1e30f};
    float l_i[4] = {0.f, 0.f, 0.f, 0.f};
    f32x4 acc[4];
    #pragma unroll
    for (int nb = 0; nb < 4; nb++) acc[nb] = f32x4{0.f, 0.f, 0.f, 0.f};

    for (int ck = 0; ck < 8; ck++) {
        __syncthreads();
        #pragma unroll
        for (int p = 0; p < 4; p++) {
            const int idx = p * 256 + tid;
            const int keyl = idx >> 3, dc = idx & 7;
            const bf16x8 v = *(const bf16x8*)&base[(size_t)(ck*128 + keyl) * 3072 + 2048 + h*64 + dc*8];
            #pragma unroll
            for (int e = 0; e < 8; e++) Vt[dc*8 + e][keyl] = v[e];
        }
        __syncthreads();
        for (int kk = 0; kk < 4; kk++) {
            const int key0 = ck * 128 + kk * 32;
            f32x4 s0, s1;
            {
                const int keyA = key0 + (lane & 15);
                const bf16* kp = base + (size_t)keyA * 3072 + 1024 + h * 64 + ((lane >> 4) << 3);
                f32x4 z{0.f, 0.f, 0.f, 0.f};
                z = mfma16(aQ[0], *(const bf16x8*)kp, z);
                z = mfma16(aQ[1], *(const bf16x8*)(kp + 32), z);
                s0 = z;
                const bf16* kp2 = kp + (size_t)16 * 3072;
                f32x4 z2{0.f, 0.f, 0.f, 0.f};
                z2 = mfma16(aQ[0], *(const bf16x8*)kp2, z2);
                z2 = mfma16(aQ[1], *(const bf16x8*)(kp2 + 32), z2);
                s1 = z2;
            }
            float c[4];
            #pragma unroll
            for (int i = 0; i < 4; i++) {
                const float sa = s0[i] * 0.125f, sb = s1[i] * 0.125f;
                float t = fmaxf(sa, sb);
                #pragma unroll
                for (int o = 1; o < 16; o <<= 1) t = fmaxf(t, __shfl_xor(t, o));
                const float mnew = fmaxf(m_i[i], t);
                c[i] = __expf(m_i[i] - mnew);
                const float p0 = __expf(sa - mnew), p1 = __expf(sb - mnew);
                float rs = p0 + p1;
                #pragma unroll
                for (int o = 1; o < 16; o <<= 1) rs += __shfl_xor(rs, o);
                l_i[i] = l_i[i] * c[i] + rs;
                m_i[i] = mnew;
                const int pr = ((lane >> 4) << 2) + i;
                Plds[wave][pr][lane & 15]      = (bf16)p0;
                Plds[wave][pr][16 + (lane & 15)] = (bf16)p1;
            }
            #pragma unroll
            for (int nb = 0; nb < 4; nb++) {
                f32x4 a = acc[nb];
                a[0] *= c[0]; a[1] *= c[1]; a[2] *= c[2]; a[3] *= c[3];
                acc[nb] = a;
            }
            const bf16x8 aP = *(const bf16x8*)&Plds[wave][lane & 15][(lane >> 4) << 3];
            #pragma unroll
            for (int nb = 0; nb < 4; nb++) {
                const bf16x8 bV = *(const bf16x8*)&Vt[nb*16 + (lane & 15)][kk*32 + ((lane >> 4) << 3)];
                acc[nb] = mfma16(aP, bV, acc[nb]);
            }
        }
    }
    #pragma unroll
    for (int nb = 0; nb < 4; nb++) {
        #pragma unroll
        for (int i = 0; i < 4; i++) {
            const int row = qrow0 + ((lane >> 4) << 2) + i;
            const float o = acc[nb][i] / l_i[i];
            attno[(size_t)(b*1024 + row) * 1024 + h*64 + nb*16 + (lane & 15)] = (bf16)o;
        }
    }
}

// ---------------- orchestration ----------------
extern "C" void kernel_launch(void* const* d_in, const int* in_sizes, int n_in,
                              void* d_out, int out_size, void* d_ws, size_t ws_size,
                              hipStream_t stream)
{
    const int*   ids     = (const int*)  d_in[0];
    const float* tok_emb = (const float*)d_in[1];
    const float* pos_emb = (const float*)d_in[2];
    const float* ln1_s   = (const float*)d_in[3];
    const float* ln1_b   = (const float*)d_in[4];
    const float* qkv_w   = (const float*)d_in[5];
    const float* qkv_b   = (const float*)d_in[6];
    const float* out_w   = (const float*)d_in[7];
    const float* out_b   = (const float*)d_in[8];
    const float* ln2_s   = (const float*)d_in[9];
    const float* ln2_b   = (const float*)d_in[10];
    const float* w1      = (const float*)d_in[11];
    const float* b1      = (const float*)d_in[12];
    const float* w2      = (const float*)d_in[13];
    const float* b2      = (const float*)d_in[14];
    const float* lnf_s   = (const float*)d_in[15];
    const float* lnf_b   = (const float*)d_in[16];
    const float* lm_w    = (const float*)d_in[17];

    char* ws = (char*)d_ws;
    float* x    = (float*)ws;  ws += (size_t)2048 * 1024 * 4;
    bf16*  h    = (bf16*)ws;   ws += (size_t)2048 * 1024 * 2;
    bf16*  qkvb = (bf16*)ws;   ws += (size_t)2048 * 3072 * 2;
    bf16*  attno= (bf16*)ws;   ws += (size_t)2048 * 1024 * 2;
    bf16*  ff   = (bf16*)ws;   ws += (size_t)2048 * 4096 * 2;
    bf16*  wT   = (bf16*)ws;   ws += (size_t)32000 * 1024 * 2;

    embed_kernel<<<2048, 256, 0, stream>>>(ids, tok_emb, pos_emb, x);

    for (int l = 0; l < 6; l++) {
        ln_kernel<<<2048, 256, 0, stream>>>(x, ln1_s + l*1024, ln1_b + l*1024, h);
        wcvt_kernel<<<dim3(48, 16), 256, 0, stream>>>(qkv_w + (size_t)l*1024*3072, wT, 1024, 3072);
        gemm_kernel<128,128,0><<<16*24, 256, 0, stream>>>(h, wT, qkv_b + l*3072, nullptr, qkvb, nullptr, 3072, 1024);
        attn_kernel<<<dim3(32, 16), 256, 0, stream>>>(qkvb, attno);
        wcvt_kernel<<<dim3(16, 16), 256, 0, stream>>>(out_w + (size_t)l*1024*1024, wT, 1024, 1024);
        gemm_kernel<128,64,1><<<16*16, 256, 0, stream>>>(attno, wT, out_b + l*1024, x, nullptr, nullptr, 1024, 1024);
        ln_kernel<<<2048, 256, 0, stream>>>(x, ln2_s + l*1024, ln2_b + l*1024, h);
        wcvt_kernel<<<dim3(64, 16), 256, 0, stream>>>(w1 + (size_t)l*1024*4096, wT, 1024, 4096);
        gemm256_kernel<2><<<8*16, 512, 131072, stream>>>(h, wT, b1 + l*4096, ff, nullptr, 4096, 1024);
        wcvt_kernel<<<dim3(16, 64), 256, 0, stream>>>(w2 + (size_t)l*4096*1024, wT, 4096, 1024);
        gemm_kernel<128,64,1><<<16*16, 256, 0, stream>>>(ff, wT, b2 + l*1024, x, nullptr, nullptr, 1024, 4096);
    }
    ln_kernel<<<2048, 256, 0, stream>>>(x, lnf_s, lnf_b, h);
    wcvt_kernel<<<dim3(500, 16), 256, 0, stream>>>(lm_w, wT, 1024, 32000);
    gemm256_kernel<3><<<8*125, 512, 131072, stream>>>(h, wT, nullptr, nullptr, (float*)d_out, 32000, 1024);
}

// Round 4
// 1845.984 us; speedup vs baseline: 1.1082x; 1.1082x over previous
//
#include <hip/hip_runtime.h>
#include <hip/hip_bf16.h>
#include <cstdint>
#include <cstddef>

typedef __bf16 bf16;
typedef __attribute__((ext_vector_type(8))) __bf16 bf16x8;
typedef __attribute__((ext_vector_type(4))) __bf16 bf16x4;
typedef __attribute__((ext_vector_type(4))) float f32x4;

__device__ __forceinline__ f32x4 mfma16(bf16x8 a, bf16x8 b, f32x4 c) {
    return __builtin_amdgcn_mfma_f32_16x16x32_bf16(a, b, c, 0, 0, 0);
}

__device__ __forceinline__ void async_copy16(const void* g, void* l) {
    __builtin_amdgcn_global_load_lds((const __attribute__((address_space(1))) void*)g,
                                     (__attribute__((address_space(3))) void*)l,
                                     16, 0, 0);
}

// ---------------- embedding ----------------
__global__ __launch_bounds__(256)
void embed_kernel(const int* __restrict__ ids, const float* __restrict__ te,
                  const float* __restrict__ pe, float* __restrict__ x)
{
    const int row = blockIdx.x;
    const int s = row & 1023;
    const int id = ids[row];
    const f32x4* a = (const f32x4*)(te + (size_t)id * 1024);
    const f32x4* b = (const f32x4*)(pe + (size_t)s * 1024);
    f32x4* o = (f32x4*)(x + (size_t)row * 1024);
    o[threadIdx.x] = a[threadIdx.x] + b[threadIdx.x];
}

// ---------------- layernorm ----------------
__global__ __launch_bounds__(256)
void ln_kernel(const float* __restrict__ x, const float* __restrict__ sc,
               const float* __restrict__ bi, bf16* __restrict__ out)
{
    const int row = blockIdx.x, t = threadIdx.x;
    const f32x4 v = ((const f32x4*)(x + (size_t)row * 1024))[t];
    float s = v[0] + v[1] + v[2] + v[3];
    float q = v[0]*v[0] + v[1]*v[1] + v[2]*v[2] + v[3]*v[3];
    #pragma unroll
    for (int o = 1; o < 64; o <<= 1) { s += __shfl_xor(s, o); q += __shfl_xor(q, o); }
    __shared__ float red[8];
    const int wv = t >> 6, lane = t & 63;
    if (lane == 0) { red[wv] = s; red[4 + wv] = q; }
    __syncthreads();
    s = red[0] + red[1] + red[2] + red[3];
    q = red[4] + red[5] + red[6] + red[7];
    const float mean = s * (1.f / 1024.f);
    const float var  = q * (1.f / 1024.f) - mean * mean;
    const float rstd = rsqrtf(var + 1e-5f);
    const f32x4 scv = ((const f32x4*)sc)[t];
    const f32x4 biv = ((const f32x4*)bi)[t];
    bf16x4 o4;
    #pragma unroll
    for (int j = 0; j < 4; j++) o4[j] = (bf16)((v[j] - mean) * rstd * scv[j] + biv[j]);
    *(bf16x4*)(out + (size_t)row * 1024 + t * 4) = o4;
}

// ---------------- weight transpose+convert ----------------
__global__ __launch_bounds__(256)
void wcvt_kernel(const float* __restrict__ W, bf16* __restrict__ BT, int K, int N)
{
    __shared__ float tile[64][65];
    const int n0 = blockIdx.x << 6, k0 = blockIdx.y << 6;
    const int tx = threadIdx.x & 15, ty = threadIdx.x >> 4;
    #pragma unroll
    for (int r = 0; r < 4; r++) {
        const f32x4 v = *(const f32x4*)&W[(size_t)(k0 + ty + r*16) * N + n0 + tx*4];
        tile[ty + r*16][tx*4 + 0] = v[0];
        tile[ty + r*16][tx*4 + 1] = v[1];
        tile[ty + r*16][tx*4 + 2] = v[2];
        tile[ty + r*16][tx*4 + 3] = v[3];
    }
    __syncthreads();
    #pragma unroll
    for (int r = 0; r < 4; r++) {
        const int n = ty + r*16;
        bf16x4 o;
        #pragma unroll
        for (int j = 0; j < 4; j++) o[j] = (bf16)tile[tx*4 + j][n];
        *(bf16x4*)&BT[(size_t)(n0 + n) * K + k0 + tx*4] = o;
    }
}

// ---------------- 128-tile GEMM (2-barrier structure) ----------------
template<int BM, int BN, int EPI>
__global__ __launch_bounds__(256)
void gemm_kernel(const bf16* __restrict__ A, const bf16* __restrict__ BT,
                 const float* __restrict__ bias, float* __restrict__ resid,
                 bf16* __restrict__ outb, float* __restrict__ outf,
                 int N, int K)
{
    constexpr int MT = 2048 / BM;
    constexpr int WM = BM / 2, WN = BN / 2;
    constexpr int FM = WM / 16, FN = WN / 16;
    constexpr int CA = BM / 32, CB = BN / 32;
    __shared__ __align__(16) bf16 Asmem[BM * 64];
    __shared__ __align__(16) bf16 Bsmem[BN * 64];

    const int nwg = gridDim.x;
    const int q = nwg >> 3, rr = nwg & 7;
    const int xcd = blockIdx.x & 7, ix = blockIdx.x >> 3;
    const int nid = (xcd < rr ? xcd * (q + 1) : rr * (q + 1) + (xcd - rr) * q) + ix;
    const int bm = nid % MT, bn = nid / MT;

    const int tid = threadIdx.x;
    const int lane = tid & 63, wave = tid >> 6;
    const int wr = wave >> 1, wc = wave & 1;
    f32x4 acc[FM][FN];
    #pragma unroll
    for (int m = 0; m < FM; m++)
        #pragma unroll
        for (int n = 0; n < FN; n++) acc[m][n] = f32x4{0.f, 0.f, 0.f, 0.f};

    const bf16* Abase = A  + (size_t)bm * BM * K;
    const bf16* Bbase = BT + (size_t)bn * BN * K;
    const int K64 = K >> 6;
    for (int kt = 0; kt < K64; kt++) {
        __syncthreads();
        #pragma unroll
        for (int p = 0; p < CA; p++) {
            const int idx = p * 256 + tid;
            const int r = idx >> 3, c = (idx & 7) << 3;
            async_copy16(Abase + (size_t)r * K + kt * 64 + c, Asmem + idx * 8);
        }
        #pragma unroll
        for (int p = 0; p < CB; p++) {
            const int idx = p * 256 + tid;
            const int r = idx >> 3, c = (idx & 7) << 3;
            async_copy16(Bbase + (size_t)r * K + kt * 64 + c, Bsmem + idx * 8);
        }
        __syncthreads();
        #pragma unroll
        for (int ks = 0; ks < 2; ks++) {
            bf16x8 af[FM], bfv[FN];
            const int ko = ks * 32 + ((lane >> 4) << 3);
            const int ar = wr * WM + (lane & 15);
            const int br = wc * WN + (lane & 15);
            #pragma unroll
            for (int m = 0; m < FM; m++) af[m]  = *(const bf16x8*)&Asmem[(ar + m*16) * 64 + ko];
            #pragma unroll
            for (int n = 0; n < FN; n++) bfv[n] = *(const bf16x8*)&Bsmem[(br + n*16) * 64 + ko];
            #pragma unroll
            for (int m = 0; m < FM; m++)
                #pragma unroll
                for (int n = 0; n < FN; n++)
                    acc[m][n] = mfma16(af[m], bfv[n], acc[m][n]);
        }
    }
    const int r0 = bm * BM + wr * WM + ((lane >> 4) << 2);
    const int c0 = bn * BN + wc * WN + (lane & 15);
    #pragma unroll
    for (int n = 0; n < FN; n++) {
        const int col = c0 + n * 16;
        const float bv = (EPI == 3) ? 0.f : bias[col];
        #pragma unroll
        for (int m = 0; m < FM; m++) {
            const int row = r0 + m * 16;
            const f32x4 a = acc[m][n];
            #pragma unroll
            for (int i = 0; i < 4; i++) {
                const float v = a[i] + bv;
                const size_t off = (size_t)(row + i) * N + col;
                if constexpr (EPI == 0) outb[off] = (bf16)v;
                else if constexpr (EPI == 1) resid[off] += v;
                else if constexpr (EPI == 2) {
                    const float g = 0.5f * v * (1.f + erff(v * 0.70710678118f));
                    outb[off] = (bf16)g;
                } else outf[off] = v;
            }
        }
    }
}

// ---------------- 256x256 8-phase GEMM v2 (m201 geometry), M mult of 256, K mult of 64 ----
// Half-tiles are M-split: [128 rows][64 k] = 16 KB, 128 B rows -> XOR(row&7) chunk swizzle
// (2-way residual conflict = free). Swizzle applied on BOTH global source and ds_read.
// All 8 staging loads for tile t+1 issued at top of tile t (4 phases of slack), single
// vmcnt(0) drain at tile end (loads long landed). Raw s_barrier; setprio around MFMA.
template<int EPI>
__global__ __launch_bounds__(512, 2)
void gemm256_kernel(const bf16* __restrict__ A, const bf16* __restrict__ BT,
                    const float* __restrict__ bias,
                    bf16* __restrict__ outb, float* __restrict__ outf,
                    int N, int K)
{
    extern __shared__ __align__(16) char smem_raw[];
    bf16* smem = (bf16*)smem_raw;

    const int nwg = gridDim.x;
    const int q = nwg >> 3, rr = nwg & 7;
    const int xcd = blockIdx.x & 7, ix = blockIdx.x >> 3;
    const int nid = (xcd < rr ? xcd * (q + 1) : rr * (q + 1) + (xcd - rr) * q) + ix;
    const int bm = nid & 7, bn = nid >> 3;    // M fastest: 8 m-tiles of 256

    const int tid = threadIdx.x, lane = tid & 63, wave = tid >> 6;
    const int wr = wave >> 2, wc = wave & 3;  // 2 M-waves x 4 N-waves, 128x64 per wave

    f32x4 acc[8][4];
    #pragma unroll
    for (int m = 0; m < 8; m++)
        #pragma unroll
        for (int n = 0; n < 4; n++) acc[m][n] = f32x4{0.f, 0.f, 0.f, 0.f};

    const bf16* Abase = A  + (size_t)bm * 256 * K;
    const bf16* Bbase = BT + (size_t)bn * 256 * K;
    const int T = K >> 6;

    // staging: half-tile = 1024 x 16B chunks over [128 rows][8 chunks]; thread covers
    // chunks tid (rows 0..63) and tid+512 (rows 64..127); source k pre-swizzled.
    const int c0 = tid, c1 = tid + 512;
    const int r0 = c0 >> 3, k0 = ((c0 & 7) ^ (r0 & 7)) << 3;
    const int r1 = c1 >> 3, k1 = ((c1 & 7) ^ (r1 & 7)) << 3;

    // read-side swizzled chunk offsets (elements): chunk = ks*4 + (lane>>4), XOR lane&7
    const int l15 = lane & 15;
    const int swz0 = ((((lane >> 4)    ) ^ (lane & 7)) << 3);
    const int swz1 = (((4 + (lane >> 4)) ^ (lane & 7)) << 3);
    const int ah = wr;                 // A half (rows wr*128..)
    const int bh = wc >> 1;            // B half
    const int bro = (wc & 1) * 64 + l15;

#define ABASE_(b_, h_) ((((b_)*2 + (h_)) << 13))
#define BBASE_(b_, h_) (32768 + (((b_)*2 + (h_)) << 13))
#define STG(gsrc, ldst) { \
    async_copy16((gsrc) + (size_t)r0 * K + k0, &smem[(ldst) + c0*8]); \
    async_copy16((gsrc) + (size_t)r1 * K + k1, &smem[(ldst) + c1*8]); }
#define STAGE_ALL(t_) { const int b_ = (t_) & 1; const size_t kc = (size_t)(t_) * 64; \
    STG(Abase + kc,                  ABASE_(b_,0)); \
    STG(Abase + (size_t)128*K + kc,  ABASE_(b_,1)); \
    STG(Bbase + kc,                  BBASE_(b_,0)); \
    STG(Bbase + (size_t)128*K + kc,  BBASE_(b_,1)); }
#define LOAD_B(b_, swz) { _Pragma("unroll") for (int n = 0; n < 4; n++) \
    bfv[n] = *(const bf16x8*)&smem[BBASE_(b_,bh) + (bro + n*16)*64 + (swz)]; }
#define LOAD_A(b_, swz, mg) { _Pragma("unroll") for (int m = 0; m < 4; m++) \
    af[m] = *(const bf16x8*)&smem[ABASE_(b_,ah) + (l15 + (mg)*64 + m*16)*64 + (swz)]; }
#define QUAD(mg) { __builtin_amdgcn_s_setprio(1); \
    _Pragma("unroll") for (int m = 0; m < 4; m++) \
      _Pragma("unroll") for (int n = 0; n < 4; n++) \
        acc[(mg)*4 + m][n] = mfma16(af[m], bfv[n], acc[(mg)*4 + m][n]); \
    __builtin_amdgcn_s_setprio(0); }

    // prologue: stage tile 0, drain, sync
    STAGE_ALL(0);
    asm volatile("s_waitcnt vmcnt(0)" ::: "memory");
    __builtin_amdgcn_s_barrier();

    for (int t = 0; t < T; t++) {
        const int b = t & 1;
        const bool more = (t + 1) < T;
        bf16x8 af[4], bfv[4];
        if (more) STAGE_ALL(t + 1);       // 8 loads, 4 phases of slack before drain
        // ---- phase 1: ks0, m0-3 ----
        LOAD_B(b, swz0); LOAD_A(b, swz0, 0);
        __builtin_amdgcn_s_barrier();
        QUAD(0);
        __builtin_amdgcn_s_barrier();
        // ---- phase 2: ks0, m4-7 ----
        LOAD_A(b, swz0, 1);
        __builtin_amdgcn_s_barrier();
        QUAD(1);
        __builtin_amdgcn_s_barrier();
        // ---- phase 3: ks1, m0-3 ----
        LOAD_B(b, swz1); LOAD_A(b, swz1, 0);
        __builtin_amdgcn_s_barrier();
        QUAD(0);
        __builtin_amdgcn_s_barrier();
        // ---- phase 4: ks1, m4-7 ----
        LOAD_A(b, swz1, 1);
        __builtin_amdgcn_s_barrier();
        QUAD(1);
        asm volatile("s_waitcnt vmcnt(0)" ::: "memory");
        __builtin_amdgcn_s_barrier();
    }

    // epilogue: D row = (lane>>4)*4+i, col = lane&15
    const int er = bm * 256 + wr * 128 + ((lane >> 4) << 2);
    const int ec = bn * 256 + wc * 64 + l15;
    #pragma unroll
    for (int n = 0; n < 4; n++) {
        const int col = ec + n * 16;
        const float bv = (EPI == 3) ? 0.f : bias[col];
        #pragma unroll
        for (int m = 0; m < 8; m++) {
            #pragma unroll
            for (int i = 0; i < 4; i++) {
                const float v = acc[m][n][i] + bv;
                const size_t off = (size_t)(er + m * 16 + i) * N + col;
                if constexpr (EPI == 2) {
                    outb[off] = (bf16)(0.5f * v * (1.f + erff(v * 0.70710678118f)));
                } else {
                    outf[off] = v;
                }
            }
        }
    }
#undef ABASE_
#undef BBASE_
#undef STG
#undef STAGE_ALL
#undef LOAD_A
#undef LOAD_B
#undef QUAD
}

// ---------------- fused non-causal attention (flash-style) ----------------
__global__ __launch_bounds__(256)
void attn_kernel(const bf16* __restrict__ qkv, bf16* __restrict__ attno)
{
    __shared__ __align__(16) bf16 Vt[64][136];
    __shared__ __align__(16) bf16 Plds[4][16][40];
    const int b = blockIdx.x >> 4, h = blockIdx.x & 15;
    const int qb = blockIdx.y;
    const int tid = threadIdx.x, lane = tid & 63, wave = tid >> 6;
    const bf16* base = qkv + (size_t)b * 1024 * 3072;
    const int qrow0 = qb * 64 + wave * 16;

    bf16x8 aQ[2];
    {
        const int qr = qrow0 + (lane & 15);
        const bf16* qp = base + (size_t)qr * 3072 + h * 64 + ((lane >> 4) << 3);
        aQ[0] = *(const bf16x8*)qp;
        aQ[1] = *(const bf16x8*)(qp + 32);
    }
    float m_i[4] = {-1e30f, -1e30f, -1e30f, -1e30f};
    float l_i[4] = {0.f, 0.f, 0.f, 0.f};
    f32x4 acc[4];
    #pragma unroll
    for (int nb = 0; nb < 4; nb++) acc[nb] = f32x4{0.f, 0.f, 0.f, 0.f};

    for (int ck = 0; ck < 8; ck++) {
        __syncthreads();
        #pragma unroll
        for (int p = 0; p < 4; p++) {
            const int idx = p * 256 + tid;
            const int keyl = idx >> 3, dc = idx & 7;
            const bf16x8 v = *(const bf16x8*)&base[(size_t)(ck*128 + keyl) * 3072 + 2048 + h*64 + dc*8];
            #pragma unroll
            for (int e = 0; e < 8; e++) Vt[dc*8 + e][keyl] = v[e];
        }
        __syncthreads();
        for (int kk = 0; kk < 4; kk++) {
            const int key0 = ck * 128 + kk * 32;
            f32x4 s0, s1;
            {
                const int keyA = key0 + (lane & 15);
                const bf16* kp = base + (size_t)keyA * 3072 + 1024 + h * 64 + ((lane >> 4) << 3);
                f32x4 z{0.f, 0.f, 0.f, 0.f};
                z = mfma16(aQ[0], *(const bf16x8*)kp, z);
                z = mfma16(aQ[1], *(const bf16x8*)(kp + 32), z);
                s0 = z;
                const bf16* kp2 = kp + (size_t)16 * 3072;
                f32x4 z2{0.f, 0.f, 0.f, 0.f};
                z2 = mfma16(aQ[0], *(const bf16x8*)kp2, z2);
                z2 = mfma16(aQ[1], *(const bf16x8*)(kp2 + 32), z2);
                s1 = z2;
            }
            float c[4];
            #pragma unroll
            for (int i = 0; i < 4; i++) {
                const float sa = s0[i] * 0.125f, sb = s1[i] * 0.125f;
                float t = fmaxf(sa, sb);
                #pragma unroll
                for (int o = 1; o < 16; o <<= 1) t = fmaxf(t, __shfl_xor(t, o));
                const float mnew = fmaxf(m_i[i], t);
                c[i] = __expf(m_i[i] - mnew);
                const float p0 = __expf(sa - mnew), p1 = __expf(sb - mnew);
                float rs = p0 + p1;
                #pragma unroll
                for (int o = 1; o < 16; o <<= 1) rs += __shfl_xor(rs, o);
                l_i[i] = l_i[i] * c[i] + rs;
                m_i[i] = mnew;
                const int pr = ((lane >> 4) << 2) + i;
                Plds[wave][pr][lane & 15]      = (bf16)p0;
                Plds[wave][pr][16 + (lane & 15)] = (bf16)p1;
            }
            #pragma unroll
            for (int nb = 0; nb < 4; nb++) {
                f32x4 a = acc[nb];
                a[0] *= c[0]; a[1] *= c[1]; a[2] *= c[2]; a[3] *= c[3];
                acc[nb] = a;
            }
            const bf16x8 aP = *(const bf16x8*)&Plds[wave][lane & 15][(lane >> 4) << 3];
            #pragma unroll
            for (int nb = 0; nb < 4; nb++) {
                const bf16x8 bV = *(const bf16x8*)&Vt[nb*16 + (lane & 15)][kk*32 + ((lane >> 4) << 3)];
                acc[nb] = mfma16(aP, bV, acc[nb]);
            }
        }
    }
    #pragma unroll
    for (int nb = 0; nb < 4; nb++) {
        #pragma unroll
        for (int i = 0; i < 4; i++) {
            const int row = qrow0 + ((lane >> 4) << 2) + i;
            const float o = acc[nb][i] / l_i[i];
            attno[(size_t)(b*1024 + row) * 1024 + h*64 + nb*16 + (lane & 15)] = (bf16)o;
        }
    }
}

// ---------------- orchestration ----------------
extern "C" void kernel_launch(void* const* d_in, const int* in_sizes, int n_in,
                              void* d_out, int out_size, void* d_ws, size_t ws_size,
                              hipStream_t stream)
{
    const int*   ids     = (const int*)  d_in[0];
    const float* tok_emb = (const float*)d_in[1];
    const float* pos_emb = (const float*)d_in[2];
    const float* ln1_s   = (const float*)d_in[3];
    const float* ln1_b   = (const float*)d_in[4];
    const float* qkv_w   = (const float*)d_in[5];
    const float* qkv_b   = (const float*)d_in[6];
    const float* out_w   = (const float*)d_in[7];
    const float* out_b   = (const float*)d_in[8];
    const float* ln2_s   = (const float*)d_in[9];
    const float* ln2_b   = (const float*)d_in[10];
    const float* w1      = (const float*)d_in[11];
    const float* b1      = (const float*)d_in[12];
    const float* w2      = (const float*)d_in[13];
    const float* b2      = (const float*)d_in[14];
    const float* lnf_s   = (const float*)d_in[15];
    const float* lnf_b   = (const float*)d_in[16];
    const float* lm_w    = (const float*)d_in[17];

    char* ws = (char*)d_ws;
    float* x    = (float*)ws;  ws += (size_t)2048 * 1024 * 4;
    bf16*  h    = (bf16*)ws;   ws += (size_t)2048 * 1024 * 2;
    bf16*  qkvb = (bf16*)ws;   ws += (size_t)2048 * 3072 * 2;
    bf16*  attno= (bf16*)ws;   ws += (size_t)2048 * 1024 * 2;
    bf16*  ff   = (bf16*)ws;   ws += (size_t)2048 * 4096 * 2;
    bf16*  wT   = (bf16*)ws;   ws += (size_t)32000 * 1024 * 2;

    embed_kernel<<<2048, 256, 0, stream>>>(ids, tok_emb, pos_emb, x);

    for (int l = 0; l < 6; l++) {
        ln_kernel<<<2048, 256, 0, stream>>>(x, ln1_s + l*1024, ln1_b + l*1024, h);
        wcvt_kernel<<<dim3(48, 16), 256, 0, stream>>>(qkv_w + (size_t)l*1024*3072, wT, 1024, 3072);
        gemm_kernel<128,128,0><<<16*24, 256, 0, stream>>>(h, wT, qkv_b + l*3072, nullptr, qkvb, nullptr, 3072, 1024);
        attn_kernel<<<dim3(32, 16), 256, 0, stream>>>(qkvb, attno);
        wcvt_kernel<<<dim3(16, 16), 256, 0, stream>>>(out_w + (size_t)l*1024*1024, wT, 1024, 1024);
        gemm_kernel<128,64,1><<<16*16, 256, 0, stream>>>(attno, wT, out_b + l*1024, x, nullptr, nullptr, 1024, 1024);
        ln_kernel<<<2048, 256, 0, stream>>>(x, ln2_s + l*1024, ln2_b + l*1024, h);
        wcvt_kernel<<<dim3(64, 16), 256, 0, stream>>>(w1 + (size_t)l*1024*4096, wT, 1024, 4096);
        gemm_kernel<128,128,2><<<16*32, 256, 0, stream>>>(h, wT, b1 + l*4096, nullptr, ff, nullptr, 4096, 1024);
        wcvt_kernel<<<dim3(16, 64), 256, 0, stream>>>(w2 + (size_t)l*4096*1024, wT, 4096, 1024);
        gemm_kernel<128,64,1><<<16*16, 256, 0, stream>>>(ff, wT, b2 + l*1024, x, nullptr, nullptr, 1024, 4096);
    }
    ln_kernel<<<2048, 256, 0, stream>>>(x, lnf_s, lnf_b, h);
    wcvt_kernel<<<dim3(500, 16), 256, 0, stream>>>(lm_w, wT, 1024, 32000);
    gemm256_kernel<3><<<8*125, 512, 131072, stream>>>(h, wT, nullptr, nullptr, (float*)d_out, 32000, 1024);
}

// Round 5
// 1805.451 us; speedup vs baseline: 1.1331x; 1.0225x over previous
//
#include <hip/hip_runtime.h>
#include <hip/hip_bf16.h>
#include <cstdint>
#include <cstddef>

typedef __bf16 bf16;
typedef __attribute__((ext_vector_type(8))) __bf16 bf16x8;
typedef __attribute__((ext_vector_type(4))) __bf16 bf16x4;
typedef __attribute__((ext_vector_type(4))) float f32x4;

__device__ __forceinline__ f32x4 mfma16(bf16x8 a, bf16x8 b, f32x4 c) {
    return __builtin_amdgcn_mfma_f32_16x16x32_bf16(a, b, c, 0, 0, 0);
}

__device__ __forceinline__ void async_copy16(const void* g, void* l) {
    __builtin_amdgcn_global_load_lds((const __attribute__((address_space(1))) void*)g,
                                     (__attribute__((address_space(3))) void*)l,
                                     16, 0, 0);
}

template<int Ncnt> __device__ __forceinline__ void waitv();
template<> __device__ __forceinline__ void waitv<0>() { asm volatile("s_waitcnt vmcnt(0)" ::: "memory"); }
template<> __device__ __forceinline__ void waitv<3>() { asm volatile("s_waitcnt vmcnt(3)" ::: "memory"); }
template<> __device__ __forceinline__ void waitv<4>() { asm volatile("s_waitcnt vmcnt(4)" ::: "memory"); }

// ---------------- embedding ----------------
__global__ __launch_bounds__(256)
void embed_kernel(const int* __restrict__ ids, const float* __restrict__ te,
                  const float* __restrict__ pe, float* __restrict__ x)
{
    const int row = blockIdx.x;
    const int s = row & 1023;
    const int id = ids[row];
    const f32x4* a = (const f32x4*)(te + (size_t)id * 1024);
    const f32x4* b = (const f32x4*)(pe + (size_t)s * 1024);
    f32x4* o = (f32x4*)(x + (size_t)row * 1024);
    o[threadIdx.x] = a[threadIdx.x] + b[threadIdx.x];
}

// ---------------- layernorm ----------------
__global__ __launch_bounds__(256)
void ln_kernel(const float* __restrict__ x, const float* __restrict__ sc,
               const float* __restrict__ bi, bf16* __restrict__ out)
{
    const int row = blockIdx.x, t = threadIdx.x;
    const f32x4 v = ((const f32x4*)(x + (size_t)row * 1024))[t];
    float s = v[0] + v[1] + v[2] + v[3];
    float q = v[0]*v[0] + v[1]*v[1] + v[2]*v[2] + v[3]*v[3];
    #pragma unroll
    for (int o = 1; o < 64; o <<= 1) { s += __shfl_xor(s, o); q += __shfl_xor(q, o); }
    __shared__ float red[8];
    const int wv = t >> 6, lane = t & 63;
    if (lane == 0) { red[wv] = s; red[4 + wv] = q; }
    __syncthreads();
    s = red[0] + red[1] + red[2] + red[3];
    q = red[4] + red[5] + red[6] + red[7];
    const float mean = s * (1.f / 1024.f);
    const float var  = q * (1.f / 1024.f) - mean * mean;
    const float rstd = rsqrtf(var + 1e-5f);
    const f32x4 scv = ((const f32x4*)sc)[t];
    const f32x4 biv = ((const f32x4*)bi)[t];
    bf16x4 o4;
    #pragma unroll
    for (int j = 0; j < 4; j++) o4[j] = (bf16)((v[j] - mean) * rstd * scv[j] + biv[j]);
    *(bf16x4*)(out + (size_t)row * 1024 + t * 4) = o4;
}

// ---------------- weight transpose+convert ----------------
__global__ __launch_bounds__(256)
void wcvt_kernel(const float* __restrict__ W, bf16* __restrict__ BT, int K, int N)
{
    __shared__ float tile[64][65];
    const int n0 = blockIdx.x << 6, k0 = blockIdx.y << 6;
    const int tx = threadIdx.x & 15, ty = threadIdx.x >> 4;
    #pragma unroll
    for (int r = 0; r < 4; r++) {
        const f32x4 v = *(const f32x4*)&W[(size_t)(k0 + ty + r*16) * N + n0 + tx*4];
        tile[ty + r*16][tx*4 + 0] = v[0];
        tile[ty + r*16][tx*4 + 1] = v[1];
        tile[ty + r*16][tx*4 + 2] = v[2];
        tile[ty + r*16][tx*4 + 3] = v[3];
    }
    __syncthreads();
    #pragma unroll
    for (int r = 0; r < 4; r++) {
        const int n = ty + r*16;
        bf16x4 o;
        #pragma unroll
        for (int j = 0; j < 4; j++) o[j] = (bf16)tile[tx*4 + j][n];
        *(bf16x4*)&BT[(size_t)(n0 + n) * K + k0 + tx*4] = o;
    }
}

// ---------------- 128-tile GEMM (2-barrier structure) ----------------
template<int BM, int BN, int EPI>
__global__ __launch_bounds__(256)
void gemm_kernel(const bf16* __restrict__ A, const bf16* __restrict__ BT,
                 const float* __restrict__ bias, float* __restrict__ resid,
                 bf16* __restrict__ outb, float* __restrict__ outf,
                 int N, int K)
{
    constexpr int MT = 2048 / BM;
    constexpr int WM = BM / 2, WN = BN / 2;
    constexpr int FM = WM / 16, FN = WN / 16;
    constexpr int CA = BM / 32, CB = BN / 32;
    __shared__ __align__(16) bf16 Asmem[BM * 64];
    __shared__ __align__(16) bf16 Bsmem[BN * 64];

    const int nwg = gridDim.x;
    const int q = nwg >> 3, rr = nwg & 7;
    const int xcd = blockIdx.x & 7, ix = blockIdx.x >> 3;
    const int nid = (xcd < rr ? xcd * (q + 1) : rr * (q + 1) + (xcd - rr) * q) + ix;
    const int bm = nid % MT, bn = nid / MT;

    const int tid = threadIdx.x;
    const int lane = tid & 63, wave = tid >> 6;
    const int wr = wave >> 1, wc = wave & 1;
    f32x4 acc[FM][FN];
    #pragma unroll
    for (int m = 0; m < FM; m++)
        #pragma unroll
        for (int n = 0; n < FN; n++) acc[m][n] = f32x4{0.f, 0.f, 0.f, 0.f};

    const bf16* Abase = A  + (size_t)bm * BM * K;
    const bf16* Bbase = BT + (size_t)bn * BN * K;
    const int K64 = K >> 6;
    for (int kt = 0; kt < K64; kt++) {
        __syncthreads();
        #pragma unroll
        for (int p = 0; p < CA; p++) {
            const int idx = p * 256 + tid;
            const int r = idx >> 3, c = (idx & 7) << 3;
            async_copy16(Abase + (size_t)r * K + kt * 64 + c, Asmem + idx * 8);
        }
        #pragma unroll
        for (int p = 0; p < CB; p++) {
            const int idx = p * 256 + tid;
            const int r = idx >> 3, c = (idx & 7) << 3;
            async_copy16(Bbase + (size_t)r * K + kt * 64 + c, Bsmem + idx * 8);
        }
        __syncthreads();
        #pragma unroll
        for (int ks = 0; ks < 2; ks++) {
            bf16x8 af[FM], bfv[FN];
            const int ko = ks * 32 + ((lane >> 4) << 3);
            const int ar = wr * WM + (lane & 15);
            const int br = wc * WN + (lane & 15);
            #pragma unroll
            for (int m = 0; m < FM; m++) af[m]  = *(const bf16x8*)&Asmem[(ar + m*16) * 64 + ko];
            #pragma unroll
            for (int n = 0; n < FN; n++) bfv[n] = *(const bf16x8*)&Bsmem[(br + n*16) * 64 + ko];
            #pragma unroll
            for (int m = 0; m < FM; m++)
                #pragma unroll
                for (int n = 0; n < FN; n++)
                    acc[m][n] = mfma16(af[m], bfv[n], acc[m][n]);
        }
    }
    const int r0 = bm * BM + wr * WM + ((lane >> 4) << 2);
    const int c0 = bn * BN + wc * WN + (lane & 15);
    #pragma unroll
    for (int n = 0; n < FN; n++) {
        const int col = c0 + n * 16;
        const float bv = (EPI == 3) ? 0.f : bias[col];
        #pragma unroll
        for (int m = 0; m < FM; m++) {
            const int row = r0 + m * 16;
            const f32x4 a = acc[m][n];
            #pragma unroll
            for (int i = 0; i < 4; i++) {
                const float v = a[i] + bv;
                const size_t off = (size_t)(row + i) * N + col;
                if constexpr (EPI == 0) outb[off] = (bf16)v;
                else if constexpr (EPI == 1) resid[off] += v;
                else if constexpr (EPI == 2) {
                    const float g = 0.5f * v * (1.f + erff(v * 0.70710678118f));
                    outb[off] = (bf16)g;
                } else outf[off] = v;
            }
        }
    }
}

// ---------------- 8-phase GEMM v3: counted vmcnt, never 0 mid-loop (T3+T4) ----------------
// Sub-K staging: A/B sub-tiles [R][32 k] (4x16B chunks/row), XOR chunk ^= (row>>1)&3
// (2-way residual = free), applied identically on global source and ds_read.
// Per tile t: ph1 stages A_ks0(t+1), ph2 B_ks0(t+1), ph3 A_ks1(t+1), ph4 B_ks1(t+1);
// waits vmcnt(LA+LB) ONLY at ph2-end (ks1(t) landed) and ph4-end (ks0(t+1) landed).
// Wave waits its own counter, then s_barrier makes it collective.
template<int BM, int BN, int EPI>
__global__ __launch_bounds__(512, 2)
void gemm256_kernel(const bf16* __restrict__ A, const bf16* __restrict__ BT,
                    const float* __restrict__ bias,
                    bf16* __restrict__ outb, float* __restrict__ outf,
                    int N, int K)
{
    constexpr int MT = 2048 / BM;
    constexpr int FM = BM / 32;          // per-wave m-frags (wave owns BM/2 rows)
    constexpr int FN = BN / 64;          // per-wave n-frags (wave owns BN/4 cols)
    constexpr int HM = FM / 2;
    constexpr int LA = BM / 128, LB = BN / 128;  // loads/thread per sub-K sub-tile
    constexpr int ASUB = BM * 32;        // elements per A sub-tile
    constexpr int BSUB = BN * 32;
    extern __shared__ __align__(16) char smem_raw[];
    bf16* smem = (bf16*)smem_raw;

    const int nwg = gridDim.x;
    const int q = nwg >> 3, rr = nwg & 7;
    const int xcd = blockIdx.x & 7, ix = blockIdx.x >> 3;
    const int nid = (xcd < rr ? xcd * (q + 1) : rr * (q + 1) + (xcd - rr) * q) + ix;
    const int bm = nid % MT, bn = nid / MT;

    const int tid = threadIdx.x, lane = tid & 63, wave = tid >> 6;
    const int wr = wave >> 2, wc = wave & 3;   // 2 M-waves x 4 N-waves

    f32x4 acc[FM][FN];
    #pragma unroll
    for (int m = 0; m < FM; m++)
        #pragma unroll
        for (int n = 0; n < FN; n++) acc[m][n] = f32x4{0.f, 0.f, 0.f, 0.f};

    const bf16* Abase = A  + (size_t)bm * BM * K;
    const bf16* Bbase = BT + (size_t)bn * BN * K;
    const int T = K >> 6;

    // read-side: one lane-constant swizzled chunk offset (elements)
    const int l15 = lane & 15;
    const int swz = (((lane >> 4) ^ ((l15 >> 1) & 3)) << 3);
    const int arow0 = wr * (BM / 2) + l15;
    const int brow0 = wc * (BN / 4) + l15;

#define ABASE_(b_, ks_) (((b_)*2 + (ks_)) * ASUB)
#define BBASE_(b_, ks_) (4*ASUB + ((b_)*2 + (ks_)) * BSUB)
#define STAGE_A(tt, ks_) { _Pragma("unroll") for (int i = 0; i < LA; i++) { \
    const int c = tid + i * 512; const int rw = c >> 2; \
    const int kc = (c & 3) ^ ((rw >> 1) & 3); \
    async_copy16(Abase + (size_t)rw * K + (tt)*64 + (ks_)*32 + kc*8, \
                 &smem[ABASE_((tt)&1, ks_) + c*8]); } }
#define STAGE_B(tt, ks_) { _Pragma("unroll") for (int i = 0; i < LB; i++) { \
    const int c = tid + i * 512; const int rw = c >> 2; \
    const int kc = (c & 3) ^ ((rw >> 1) & 3); \
    async_copy16(Bbase + (size_t)rw * K + (tt)*64 + (ks_)*32 + kc*8, \
                 &smem[BBASE_((tt)&1, ks_) + c*8]); } }
#define LOAD_B(b_, ks_) { _Pragma("unroll") for (int n = 0; n < FN; n++) \
    bfv[n] = *(const bf16x8*)&smem[BBASE_(b_, ks_) + (brow0 + n*16)*32 + swz]; }
#define LOAD_A(b_, ks_, mg) { _Pragma("unroll") for (int m = 0; m < HM; m++) \
    af[m] = *(const bf16x8*)&smem[ABASE_(b_, ks_) + (arow0 + ((mg)*HM + m)*16)*32 + swz]; }
#define QUAD(mg) { __builtin_amdgcn_s_setprio(1); \
    _Pragma("unroll") for (int m = 0; m < HM; m++) \
      _Pragma("unroll") for (int n = 0; n < FN; n++) \
        acc[(mg)*HM + m][n] = mfma16(af[m], bfv[n], acc[(mg)*HM + m][n]); \
    __builtin_amdgcn_s_setprio(0); }

    // prologue: stage tile 0 (ks0 then ks1); wait for ks0 only (ks1 stays in flight)
    STAGE_A(0, 0); STAGE_B(0, 0); STAGE_A(0, 1); STAGE_B(0, 1);
    waitv<LA + LB>();
    __builtin_amdgcn_s_barrier();

    for (int t = 0; t < T; t++) {
        const int b = t & 1;
        const bool more = (t + 1) < T;
        bf16x8 af[HM], bfv[FN];
        // ---- phase 1: ks0, m-group 0 ----
        LOAD_B(b, 0); LOAD_A(b, 0, 0);
        if (more) STAGE_A(t + 1, 0);
        __builtin_amdgcn_s_barrier();
        QUAD(0);
        __builtin_amdgcn_s_barrier();
        // ---- phase 2: ks0, m-group 1 ----
        LOAD_A(b, 0, 1);
        if (more) STAGE_B(t + 1, 0);
        __builtin_amdgcn_s_barrier();
        QUAD(1);
        if (more) waitv<LA + LB>(); else waitv<0>();   // ks1(t) landed
        __builtin_amdgcn_s_barrier();
        // ---- phase 3: ks1, m-group 0 ----
        LOAD_B(b, 1); LOAD_A(b, 1, 0);
        if (more) STAGE_A(t + 1, 1);
        __builtin_amdgcn_s_barrier();
        QUAD(0);
        __builtin_amdgcn_s_barrier();
        // ---- phase 4: ks1, m-group 1 ----
        LOAD_A(b, 1, 1);
        if (more) STAGE_B(t + 1, 1);
        __builtin_amdgcn_s_barrier();
        QUAD(1);
        if (more) waitv<LA + LB>();                    // ks0(t+1) landed
        __builtin_amdgcn_s_barrier();
    }

    // epilogue: D row = (lane>>4)*4+i, col = lane&15
    const int er = bm * BM + wr * (BM / 2) + ((lane >> 4) << 2);
    const int ec = bn * BN + wc * (BN / 4) + l15;
    #pragma unroll
    for (int n = 0; n < FN; n++) {
        const int col = ec + n * 16;
        const float bv = (EPI == 3) ? 0.f : bias[col];
        #pragma unroll
        for (int m = 0; m < FM; m++) {
            #pragma unroll
            for (int i = 0; i < 4; i++) {
                const float v = acc[m][n][i] + bv;
                const size_t off = (size_t)(er + m * 16 + i) * N + col;
                if constexpr (EPI == 2) {
                    outb[off] = (bf16)(0.5f * v * (1.f + erff(v * 0.70710678118f)));
                } else {
                    outf[off] = v;
                }
            }
        }
    }
#undef ABASE_
#undef BBASE_
#undef STAGE_A
#undef STAGE_B
#undef LOAD_A
#undef LOAD_B
#undef QUAD
}

// ---------------- fused non-causal attention (flash-style) ----------------
__global__ __launch_bounds__(256)
void attn_kernel(const bf16* __restrict__ qkv, bf16* __restrict__ attno)
{
    __shared__ __align__(16) bf16 Vt[64][136];
    __shared__ __align__(16) bf16 Plds[4][16][40];
    const int b = blockIdx.x >> 4, h = blockIdx.x & 15;
    const int qb = blockIdx.y;
    const int tid = threadIdx.x, lane = tid & 63, wave = tid >> 6;
    const bf16* base = qkv + (size_t)b * 1024 * 3072;
    const int qrow0 = qb * 64 + wave * 16;

    bf16x8 aQ[2];
    {
        const int qr = qrow0 + (lane & 15);
        const bf16* qp = base + (size_t)qr * 3072 + h * 64 + ((lane >> 4) << 3);
        aQ[0] = *(const bf16x8*)qp;
        aQ[1] = *(const bf16x8*)(qp + 32);
    }
    float m_i[4] = {-1e30f, -1e30f, -1e30f, -1e30f};
    float l_i[4] = {0.f, 0.f, 0.f, 0.f};
    f32x4 acc[4];
    #pragma unroll
    for (int nb = 0; nb < 4; nb++) acc[nb] = f32x4{0.f, 0.f, 0.f, 0.f};

    for (int ck = 0; ck < 8; ck++) {
        __syncthreads();
        #pragma unroll
        for (int p = 0; p < 4; p++) {
            const int idx = p * 256 + tid;
            const int keyl = idx >> 3, dc = idx & 7;
            const bf16x8 v = *(const bf16x8*)&base[(size_t)(ck*128 + keyl) * 3072 + 2048 + h*64 + dc*8];
            #pragma unroll
            for (int e = 0; e < 8; e++) Vt[dc*8 + e][keyl] = v[e];
        }
        __syncthreads();
        for (int kk = 0; kk < 4; kk++) {
            const int key0 = ck * 128 + kk * 32;
            f32x4 s0, s1;
            {
                const int keyA = key0 + (lane & 15);
                const bf16* kp = base + (size_t)keyA * 3072 + 1024 + h * 64 + ((lane >> 4) << 3);
                f32x4 z{0.f, 0.f, 0.f, 0.f};
                z = mfma16(aQ[0], *(const bf16x8*)kp, z);
                z = mfma16(aQ[1], *(const bf16x8*)(kp + 32), z);
                s0 = z;
                const bf16* kp2 = kp + (size_t)16 * 3072;
                f32x4 z2{0.f, 0.f, 0.f, 0.f};
                z2 = mfma16(aQ[0], *(const bf16x8*)kp2, z2);
                z2 = mfma16(aQ[1], *(const bf16x8*)(kp2 + 32), z2);
                s1 = z2;
            }
            float c[4];
            #pragma unroll
            for (int i = 0; i < 4; i++) {
                const float sa = s0[i] * 0.125f, sb = s1[i] * 0.125f;
                float t = fmaxf(sa, sb);
                #pragma unroll
                for (int o = 1; o < 16; o <<= 1) t = fmaxf(t, __shfl_xor(t, o));
                const float mnew = fmaxf(m_i[i], t);
                c[i] = __expf(m_i[i] - mnew);
                const float p0 = __expf(sa - mnew), p1 = __expf(sb - mnew);
                float rs = p0 + p1;
                #pragma unroll
                for (int o = 1; o < 16; o <<= 1) rs += __shfl_xor(rs, o);
                l_i[i] = l_i[i] * c[i] + rs;
                m_i[i] = mnew;
                const int pr = ((lane >> 4) << 2) + i;
                Plds[wave][pr][lane & 15]      = (bf16)p0;
                Plds[wave][pr][16 + (lane & 15)] = (bf16)p1;
            }
            #pragma unroll
            for (int nb = 0; nb < 4; nb++) {
                f32x4 a = acc[nb];
                a[0] *= c[0]; a[1] *= c[1]; a[2] *= c[2]; a[3] *= c[3];
                acc[nb] = a;
            }
            const bf16x8 aP = *(const bf16x8*)&Plds[wave][lane & 15][(lane >> 4) << 3];
            #pragma unroll
            for (int nb = 0; nb < 4; nb++) {
                const bf16x8 bV = *(const bf16x8*)&Vt[nb*16 + (lane & 15)][kk*32 + ((lane >> 4) << 3)];
                acc[nb] = mfma16(aP, bV, acc[nb]);
            }
        }
    }
    #pragma unroll
    for (int nb = 0; nb < 4; nb++) {
        #pragma unroll
        for (int i = 0; i < 4; i++) {
            const int row = qrow0 + ((lane >> 4) << 2) + i;
            const float o = acc[nb][i] / l_i[i];
            attno[(size_t)(b*1024 + row) * 1024 + h*64 + nb*16 + (lane & 15)] = (bf16)o;
        }
    }
}

// ---------------- orchestration ----------------
extern "C" void kernel_launch(void* const* d_in, const int* in_sizes, int n_in,
                              void* d_out, int out_size, void* d_ws, size_t ws_size,
                              hipStream_t stream)
{
    const int*   ids     = (const int*)  d_in[0];
    const float* tok_emb = (const float*)d_in[1];
    const float* pos_emb = (const float*)d_in[2];
    const float* ln1_s   = (const float*)d_in[3];
    const float* ln1_b   = (const float*)d_in[4];
    const float* qkv_w   = (const float*)d_in[5];
    const float* qkv_b   = (const float*)d_in[6];
    const float* out_w   = (const float*)d_in[7];
    const float* out_b   = (const float*)d_in[8];
    const float* ln2_s   = (const float*)d_in[9];
    const float* ln2_b   = (const float*)d_in[10];
    const float* w1      = (const float*)d_in[11];
    const float* b1      = (const float*)d_in[12];
    const float* w2      = (const float*)d_in[13];
    const float* b2      = (const float*)d_in[14];
    const float* lnf_s   = (const float*)d_in[15];
    const float* lnf_b   = (const float*)d_in[16];
    const float* lm_w    = (const float*)d_in[17];

    char* ws = (char*)d_ws;
    float* x    = (float*)ws;  ws += (size_t)2048 * 1024 * 4;
    bf16*  h    = (bf16*)ws;   ws += (size_t)2048 * 1024 * 2;
    bf16*  qkvb = (bf16*)ws;   ws += (size_t)2048 * 3072 * 2;
    bf16*  attno= (bf16*)ws;   ws += (size_t)2048 * 1024 * 2;
    bf16*  ff   = (bf16*)ws;   ws += (size_t)2048 * 4096 * 2;
    bf16*  wT   = (bf16*)ws;   ws += (size_t)32000 * 1024 * 2;

    embed_kernel<<<2048, 256, 0, stream>>>(ids, tok_emb, pos_emb, x);

    for (int l = 0; l < 6; l++) {
        ln_kernel<<<2048, 256, 0, stream>>>(x, ln1_s + l*1024, ln1_b + l*1024, h);
        wcvt_kernel<<<dim3(48, 16), 256, 0, stream>>>(qkv_w + (size_t)l*1024*3072, wT, 1024, 3072);
        gemm_kernel<128,128,0><<<16*24, 256, 0, stream>>>(h, wT, qkv_b + l*3072, nullptr, qkvb, nullptr, 3072, 1024);
        attn_kernel<<<dim3(32, 16), 256, 0, stream>>>(qkvb, attno);
        wcvt_kernel<<<dim3(16, 16), 256, 0, stream>>>(out_w + (size_t)l*1024*1024, wT, 1024, 1024);
        gemm_kernel<128,64,1><<<16*16, 256, 0, stream>>>(attno, wT, out_b + l*1024, x, nullptr, nullptr, 1024, 1024);
        ln_kernel<<<2048, 256, 0, stream>>>(x, ln2_s + l*1024, ln2_b + l*1024, h);
        wcvt_kernel<<<dim3(64, 16), 256, 0, stream>>>(w1 + (size_t)l*1024*4096, wT, 1024, 4096);
        gemm256_kernel<128,256,2><<<256, 512, 98304, stream>>>(h, wT, b1 + l*4096, ff, nullptr, 4096, 1024);
        wcvt_kernel<<<dim3(16, 64), 256, 0, stream>>>(w2 + (size_t)l*4096*1024, wT, 4096, 1024);
        gemm_kernel<128,64,1><<<16*16, 256, 0, stream>>>(ff, wT, b2 + l*1024, x, nullptr, nullptr, 1024, 4096);
    }
    ln_kernel<<<2048, 256, 0, stream>>>(x, lnf_s, lnf_b, h);
    wcvt_kernel<<<dim3(500, 16), 256, 0, stream>>>(lm_w, wT, 1024, 32000);
    gemm256_kernel<256,256,3><<<8*125, 512, 131072, stream>>>(h, wT, nullptr, nullptr, (float*)d_out, 32000, 1024);
}

// Round 6
// 1462.563 us; speedup vs baseline: 1.3987x; 1.2344x over previous
//
#include <hip/hip_runtime.h>
#include <hip/hip_bf16.h>
#include <cstdint>
#include <cstddef>

typedef __bf16 bf16;
typedef __attribute__((ext_vector_type(8))) __bf16 bf16x8;
typedef __attribute__((ext_vector_type(4))) __bf16 bf16x4;
typedef __attribute__((ext_vector_type(4))) float f32x4;

__device__ __forceinline__ f32x4 mfma16(bf16x8 a, bf16x8 b, f32x4 c) {
    return __builtin_amdgcn_mfma_f32_16x16x32_bf16(a, b, c, 0, 0, 0);
}

__device__ __forceinline__ void async_copy16(const void* g, void* l) {
    __builtin_amdgcn_global_load_lds((const __attribute__((address_space(1))) void*)g,
                                     (__attribute__((address_space(3))) void*)l,
                                     16, 0, 0);
}

template<int Ncnt> __device__ __forceinline__ void waitv();
template<> __device__ __forceinline__ void waitv<0>() { asm volatile("s_waitcnt vmcnt(0)" ::: "memory"); }
template<> __device__ __forceinline__ void waitv<3>() { asm volatile("s_waitcnt vmcnt(3)" ::: "memory"); }
template<> __device__ __forceinline__ void waitv<4>() { asm volatile("s_waitcnt vmcnt(4)" ::: "memory"); }

// ---------------- embedding ----------------
__global__ __launch_bounds__(256)
void embed_kernel(const int* __restrict__ ids, const float* __restrict__ te,
                  const float* __restrict__ pe, float* __restrict__ x)
{
    const int row = blockIdx.x;
    const int s = row & 1023;
    const int id = ids[row];
    const f32x4* a = (const f32x4*)(te + (size_t)id * 1024);
    const f32x4* b = (const f32x4*)(pe + (size_t)s * 1024);
    f32x4* o = (f32x4*)(x + (size_t)row * 1024);
    o[threadIdx.x] = a[threadIdx.x] + b[threadIdx.x];
}

// ---------------- device bodies ----------------
__device__ __forceinline__ void ln_body(const float* __restrict__ x, const float* __restrict__ sc,
                                        const float* __restrict__ bi, bf16* __restrict__ out,
                                        int row, int t, float* red)
{
    const f32x4 v = ((const f32x4*)(x + (size_t)row * 1024))[t];
    float s = v[0] + v[1] + v[2] + v[3];
    float q = v[0]*v[0] + v[1]*v[1] + v[2]*v[2] + v[3]*v[3];
    #pragma unroll
    for (int o = 1; o < 64; o <<= 1) { s += __shfl_xor(s, o); q += __shfl_xor(q, o); }
    const int wv = t >> 6, lane = t & 63;
    if (lane == 0) { red[wv] = s; red[4 + wv] = q; }
    __syncthreads();
    s = red[0] + red[1] + red[2] + red[3];
    q = red[4] + red[5] + red[6] + red[7];
    const float mean = s * (1.f / 1024.f);
    const float var  = q * (1.f / 1024.f) - mean * mean;
    const float rstd = rsqrtf(var + 1e-5f);
    const f32x4 scv = ((const f32x4*)sc)[t];
    const f32x4 biv = ((const f32x4*)bi)[t];
    bf16x4 o4;
    #pragma unroll
    for (int j = 0; j < 4; j++) o4[j] = (bf16)((v[j] - mean) * rstd * scv[j] + biv[j]);
    *(bf16x4*)(out + (size_t)row * 1024 + t * 4) = o4;
}

__device__ __forceinline__ void wcvt_body(const float* __restrict__ W, bf16* __restrict__ BT,
                                          int K, int N, int bid, int tidx, float (*tile)[65])
{
    const int nx = N >> 6;
    const int n0 = (bid % nx) << 6, k0 = (bid / nx) << 6;
    const int tx = tidx & 15, ty = tidx >> 4;
    #pragma unroll
    for (int r = 0; r < 4; r++) {
        const f32x4 v = *(const f32x4*)&W[(size_t)(k0 + ty + r*16) * N + n0 + tx*4];
        tile[ty + r*16][tx*4 + 0] = v[0];
        tile[ty + r*16][tx*4 + 1] = v[1];
        tile[ty + r*16][tx*4 + 2] = v[2];
        tile[ty + r*16][tx*4 + 3] = v[3];
    }
    __syncthreads();
    #pragma unroll
    for (int r = 0; r < 4; r++) {
        const int n = ty + r*16;
        bf16x4 o;
        #pragma unroll
        for (int j = 0; j < 4; j++) o[j] = (bf16)tile[tx*4 + j][n];
        *(bf16x4*)&BT[(size_t)(n0 + n) * K + k0 + tx*4] = o;
    }
}

// ---------------- fused LN + up to two weight-converts ----------------
__global__ __launch_bounds__(256)
void fused_ln_wcvt(const float* __restrict__ x, const float* __restrict__ sc,
                   const float* __restrict__ bi, bf16* __restrict__ out,
                   const float* __restrict__ W1, bf16* __restrict__ BT1, int K1, int N1, int nb1,
                   const float* __restrict__ W2, bf16* __restrict__ BT2, int K2, int N2)
{
    __shared__ float tile[64][65];
    __shared__ float red[8];
    const int bid = blockIdx.x, t = threadIdx.x;
    if (bid < 2048) {
        ln_body(x, sc, bi, out, bid, t, red);
    } else {
        const int wb = bid - 2048;
        if (wb < nb1) wcvt_body(W1, BT1, K1, N1, wb, t, tile);
        else          wcvt_body(W2, BT2, K2, N2, wb - nb1, t, tile);
    }
}

// ---------------- fused attention + weight-convert ----------------
// blocks [0,512): attention (bh = bid&31, qtile = bid>>5); [512,512+nbw): wcvt.
__global__ __launch_bounds__(256)
void fused_attn_wcvt(const bf16* __restrict__ qkv, bf16* __restrict__ attno,
                     const float* __restrict__ W, bf16* __restrict__ BT, int K, int N)
{
    __shared__ __align__(16) bf16 Ksh[128 * 64];   // [key][d], chunk-XOR swizzled
    __shared__ __align__(16) bf16 Vt[64][136];     // V^T, padded
    __shared__ __align__(16) bf16 Plds[4][16][40];
    __shared__ float tile[64][65];

    const int bid = blockIdx.x, tid = threadIdx.x;
    if (bid >= 512) {
        wcvt_body(W, BT, K, N, bid - 512, tid, tile);
        return;
    }
    const int b = (bid & 31) >> 4, h = bid & 15;
    const int qb = bid >> 5;
    const int lane = tid & 63, wave = tid >> 6;
    const bf16* base = qkv + (size_t)b * 1024 * 3072;
    const int qrow0 = qb * 64 + wave * 16;

    bf16x8 aQ[2];
    {
        const int qr = qrow0 + (lane & 15);
        const bf16* qp = base + (size_t)qr * 3072 + h * 64 + ((lane >> 4) << 3);
        aQ[0] = *(const bf16x8*)qp;
        aQ[1] = *(const bf16x8*)(qp + 32);
    }
    float m_i[4] = {-1e30f, -1e30f, -1e30f, -1e30f};
    float l_i[4] = {0.f, 0.f, 0.f, 0.f};
    f32x4 acc[4];
    #pragma unroll
    for (int nb = 0; nb < 4; nb++) acc[nb] = f32x4{0.f, 0.f, 0.f, 0.f};

    // swizzled read-chunk offsets for Ksh (2-way residual conflict = free)
    const int swzA = (((lane >> 4)     ^ (lane & 7)) << 3);
    const int swzB = (((4 + (lane >> 4)) ^ (lane & 7)) << 3);

    for (int ck = 0; ck < 8; ck++) {
        __syncthreads();
        // stage K[128 keys][64 d] via global_load_lds, source chunk pre-swizzled
        #pragma unroll
        for (int p = 0; p < 4; p++) {
            const int c = p * 256 + tid;
            const int rw = c >> 3;
            const int kc = (c & 7) ^ (rw & 7);
            async_copy16(base + (size_t)(ck*128 + rw) * 3072 + 1024 + h*64 + kc*8, &Ksh[c * 8]);
        }
        // stage Vt[d][key] (manual transpose)
        #pragma unroll
        for (int p = 0; p < 4; p++) {
            const int idx = p * 256 + tid;
            const int keyl = idx >> 3, dc = idx & 7;
            const bf16x8 v = *(const bf16x8*)&base[(size_t)(ck*128 + keyl) * 3072 + 2048 + h*64 + dc*8];
            #pragma unroll
            for (int e = 0; e < 8; e++) Vt[dc*8 + e][keyl] = v[e];
        }
        __syncthreads();   // drains vmcnt+lgkm (incl. global_load_lds)
        for (int kk = 0; kk < 4; kk++) {
            f32x4 s0, s1;
            {
                const int kr0 = (kk*32 + (lane & 15)) * 64;
                const int kr1 = kr0 + 16*64;
                f32x4 z{0.f, 0.f, 0.f, 0.f};
                z = mfma16(aQ[0], *(const bf16x8*)&Ksh[kr0 + swzA], z);
                z = mfma16(aQ[1], *(const bf16x8*)&Ksh[kr0 + swzB], z);
                s0 = z;
                f32x4 z2{0.f, 0.f, 0.f, 0.f};
                z2 = mfma16(aQ[0], *(const bf16x8*)&Ksh[kr1 + swzA], z2);
                z2 = mfma16(aQ[1], *(const bf16x8*)&Ksh[kr1 + swzB], z2);
                s1 = z2;
            }
            float c[4];
            #pragma unroll
            for (int i = 0; i < 4; i++) {
                const float sa = s0[i] * 0.125f, sb = s1[i] * 0.125f;
                float t = fmaxf(sa, sb);
                #pragma unroll
                for (int o = 1; o < 16; o <<= 1) t = fmaxf(t, __shfl_xor(t, o));
                const float mnew = fmaxf(m_i[i], t);
                c[i] = __expf(m_i[i] - mnew);
                const float p0 = __expf(sa - mnew), p1 = __expf(sb - mnew);
                float rs = p0 + p1;
                #pragma unroll
                for (int o = 1; o < 16; o <<= 1) rs += __shfl_xor(rs, o);
                l_i[i] = l_i[i] * c[i] + rs;
                m_i[i] = mnew;
                const int pr = ((lane >> 4) << 2) + i;
                Plds[wave][pr][lane & 15]        = (bf16)p0;
                Plds[wave][pr][16 + (lane & 15)] = (bf16)p1;
            }
            #pragma unroll
            for (int nb = 0; nb < 4; nb++) {
                f32x4 a = acc[nb];
                a[0] *= c[0]; a[1] *= c[1]; a[2] *= c[2]; a[3] *= c[3];
                acc[nb] = a;
            }
            const bf16x8 aP = *(const bf16x8*)&Plds[wave][lane & 15][(lane >> 4) << 3];
            #pragma unroll
            for (int nb = 0; nb < 4; nb++) {
                const bf16x8 bV = *(const bf16x8*)&Vt[nb*16 + (lane & 15)][kk*32 + ((lane >> 4) << 3)];
                acc[nb] = mfma16(aP, bV, acc[nb]);
            }
        }
    }
    #pragma unroll
    for (int nb = 0; nb < 4; nb++) {
        #pragma unroll
        for (int i = 0; i < 4; i++) {
            const int row = qrow0 + ((lane >> 4) << 2) + i;
            const float o = acc[nb][i] / l_i[i];
            attno[(size_t)(b*1024 + row) * 1024 + h*64 + nb*16 + (lane & 15)] = (bf16)o;
        }
    }
}

// ---------------- 128-tile GEMM (2-barrier), optional split-K ----------------
// EPI: 0 bias->bf16 ; 1 bias+residual-add f32 (atomic when KSPLIT>1) ; 2 bias+gelu->bf16 ; 3 f32
template<int BM, int BN, int EPI, int KSPLIT>
__global__ __launch_bounds__(256)
void gemm_kernel(const bf16* __restrict__ A, const bf16* __restrict__ BT,
                 const float* __restrict__ bias, float* __restrict__ resid,
                 bf16* __restrict__ outb, float* __restrict__ outf,
                 int N, int K)
{
    constexpr int MT = 2048 / BM;
    constexpr int WM = BM / 2, WN = BN / 2;
    constexpr int FM = WM / 16, FN = WN / 16;
    constexpr int CA = BM / 32, CB = BN / 32;
    __shared__ __align__(16) bf16 Asmem[BM * 64];
    __shared__ __align__(16) bf16 Bsmem[BN * 64];

    const int nwg = gridDim.x;
    const int q = nwg >> 3, rr = nwg & 7;
    const int xcd = blockIdx.x & 7, ix = blockIdx.x >> 3;
    const int nid = (xcd < rr ? xcd * (q + 1) : rr * (q + 1) + (xcd - rr) * q) + ix;
    constexpr int NTILES_PER_SLICE_DIV = 1;  // placeholder to keep structure clear
    (void)NTILES_PER_SLICE_DIV;
    const int tiles = nwg / KSPLIT;
    const int ks = nid / tiles;
    const int tile = nid % tiles;
    const int bm = tile % MT, bn = tile / MT;

    const int tid = threadIdx.x;
    const int lane = tid & 63, wave = tid >> 6;
    const int wr = wave >> 1, wc = wave & 1;
    f32x4 acc[FM][FN];
    #pragma unroll
    for (int m = 0; m < FM; m++)
        #pragma unroll
        for (int n = 0; n < FN; n++) acc[m][n] = f32x4{0.f, 0.f, 0.f, 0.f};

    const bf16* Abase = A  + (size_t)bm * BM * K;
    const bf16* Bbase = BT + (size_t)bn * BN * K;
    const int K64 = K >> 6;
    const int ktlo = ks * (K64 / KSPLIT), kthi = ktlo + (K64 / KSPLIT);
    for (int kt = ktlo; kt < kthi; kt++) {
        __syncthreads();
        #pragma unroll
        for (int p = 0; p < CA; p++) {
            const int idx = p * 256 + tid;
            const int r = idx >> 3, c = (idx & 7) << 3;
            async_copy16(Abase + (size_t)r * K + kt * 64 + c, Asmem + idx * 8);
        }
        #pragma unroll
        for (int p = 0; p < CB; p++) {
            const int idx = p * 256 + tid;
            const int r = idx >> 3, c = (idx & 7) << 3;
            async_copy16(Bbase + (size_t)r * K + kt * 64 + c, Bsmem + idx * 8);
        }
        __syncthreads();
        #pragma unroll
        for (int kss = 0; kss < 2; kss++) {
            bf16x8 af[FM], bfv[FN];
            const int ko = kss * 32 + ((lane >> 4) << 3);
            const int ar = wr * WM + (lane & 15);
            const int br = wc * WN + (lane & 15);
            #pragma unroll
            for (int m = 0; m < FM; m++) af[m]  = *(const bf16x8*)&Asmem[(ar + m*16) * 64 + ko];
            #pragma unroll
            for (int n = 0; n < FN; n++) bfv[n] = *(const bf16x8*)&Bsmem[(br + n*16) * 64 + ko];
            #pragma unroll
            for (int m = 0; m < FM; m++)
                #pragma unroll
                for (int n = 0; n < FN; n++)
                    acc[m][n] = mfma16(af[m], bfv[n], acc[m][n]);
        }
    }
    const int r0 = bm * BM + wr * WM + ((lane >> 4) << 2);
    const int c0 = bn * BN + wc * WN + (lane & 15);
    #pragma unroll
    for (int n = 0; n < FN; n++) {
        const int col = c0 + n * 16;
        const float bv = (EPI == 3) ? 0.f : ((KSPLIT > 1 && ks != 0) ? 0.f : bias[col]);
        #pragma unroll
        for (int m = 0; m < FM; m++) {
            const int row = r0 + m * 16;
            const f32x4 a = acc[m][n];
            #pragma unroll
            for (int i = 0; i < 4; i++) {
                const float v = a[i] + bv;
                const size_t off = (size_t)(row + i) * N + col;
                if constexpr (EPI == 0) outb[off] = (bf16)v;
                else if constexpr (EPI == 1) {
                    if constexpr (KSPLIT > 1) atomicAdd(&resid[off], v);
                    else resid[off] += v;
                }
                else if constexpr (EPI == 2) {
                    const float g = 0.5f * v * (1.f + erff(v * 0.70710678118f));
                    outb[off] = (bf16)g;
                } else outf[off] = v;
            }
        }
    }
}

// ---------------- 8-phase GEMM (T3+T4): counted vmcnt, never 0 mid-loop ----------------
template<int BM, int BN, int EPI>
__global__ __launch_bounds__(512, 2)
void gemm256_kernel(const bf16* __restrict__ A, const bf16* __restrict__ BT,
                    const float* __restrict__ bias,
                    bf16* __restrict__ outb, float* __restrict__ outf,
                    int N, int K)
{
    constexpr int MT = 2048 / BM;
    constexpr int FM = BM / 32;
    constexpr int FN = BN / 64;
    constexpr int HM = FM / 2;
    constexpr int LA = BM / 128, LB = BN / 128;
    constexpr int ASUB = BM * 32;
    constexpr int BSUB = BN * 32;
    extern __shared__ __align__(16) char smem_raw[];
    bf16* smem = (bf16*)smem_raw;

    const int nwg = gridDim.x;
    const int q = nwg >> 3, rr = nwg & 7;
    const int xcd = blockIdx.x & 7, ix = blockIdx.x >> 3;
    const int nid = (xcd < rr ? xcd * (q + 1) : rr * (q + 1) + (xcd - rr) * q) + ix;
    const int bm = nid % MT, bn = nid / MT;

    const int tid = threadIdx.x, lane = tid & 63, wave = tid >> 6;
    const int wr = wave >> 2, wc = wave & 3;

    f32x4 acc[FM][FN];
    #pragma unroll
    for (int m = 0; m < FM; m++)
        #pragma unroll
        for (int n = 0; n < FN; n++) acc[m][n] = f32x4{0.f, 0.f, 0.f, 0.f};

    const bf16* Abase = A  + (size_t)bm * BM * K;
    const bf16* Bbase = BT + (size_t)bn * BN * K;
    const int T = K >> 6;

    const int l15 = lane & 15;
    const int swz = (((lane >> 4) ^ ((l15 >> 1) & 3)) << 3);
    const int arow0 = wr * (BM / 2) + l15;
    const int brow0 = wc * (BN / 4) + l15;

#define ABASE_(b_, ks_) (((b_)*2 + (ks_)) * ASUB)
#define BBASE_(b_, ks_) (4*ASUB + ((b_)*2 + (ks_)) * BSUB)
#define STAGE_A(tt, ks_) { _Pragma("unroll") for (int i = 0; i < LA; i++) { \
    const int c = tid + i * 512; const int rw = c >> 2; \
    const int kc = (c & 3) ^ ((rw >> 1) & 3); \
    async_copy16(Abase + (size_t)rw * K + (tt)*64 + (ks_)*32 + kc*8, \
                 &smem[ABASE_((tt)&1, ks_) + c*8]); } }
#define STAGE_B(tt, ks_) { _Pragma("unroll") for (int i = 0; i < LB; i++) { \
    const int c = tid + i * 512; const int rw = c >> 2; \
    const int kc = (c & 3) ^ ((rw >> 1) & 3); \
    async_copy16(Bbase + (size_t)rw * K + (tt)*64 + (ks_)*32 + kc*8, \
                 &smem[BBASE_((tt)&1, ks_) + c*8]); } }
#define LOAD_B(b_, ks_) { _Pragma("unroll") for (int n = 0; n < FN; n++) \
    bfv[n] = *(const bf16x8*)&smem[BBASE_(b_, ks_) + (brow0 + n*16)*32 + swz]; }
#define LOAD_A(b_, ks_, mg) { _Pragma("unroll") for (int m = 0; m < HM; m++) \
    af[m] = *(const bf16x8*)&smem[ABASE_(b_, ks_) + (arow0 + ((mg)*HM + m)*16)*32 + swz]; }
#define QUAD(mg) { __builtin_amdgcn_s_setprio(1); \
    _Pragma("unroll") for (int m = 0; m < HM; m++) \
      _Pragma("unroll") for (int n = 0; n < FN; n++) \
        acc[(mg)*HM + m][n] = mfma16(af[m], bfv[n], acc[(mg)*HM + m][n]); \
    __builtin_amdgcn_s_setprio(0); }

    STAGE_A(0, 0); STAGE_B(0, 0); STAGE_A(0, 1); STAGE_B(0, 1);
    waitv<LA + LB>();
    __builtin_amdgcn_s_barrier();

    for (int t = 0; t < T; t++) {
        const int b = t & 1;
        const bool more = (t + 1) < T;
        bf16x8 af[HM], bfv[FN];
        LOAD_B(b, 0); LOAD_A(b, 0, 0);
        if (more) STAGE_A(t + 1, 0);
        __builtin_amdgcn_s_barrier();
        QUAD(0);
        __builtin_amdgcn_s_barrier();
        LOAD_A(b, 0, 1);
        if (more) STAGE_B(t + 1, 0);
        __builtin_amdgcn_s_barrier();
        QUAD(1);
        if (more) waitv<LA + LB>(); else waitv<0>();
        __builtin_amdgcn_s_barrier();
        LOAD_B(b, 1); LOAD_A(b, 1, 0);
        if (more) STAGE_A(t + 1, 1);
        __builtin_amdgcn_s_barrier();
        QUAD(0);
        __builtin_amdgcn_s_barrier();
        LOAD_A(b, 1, 1);
        if (more) STAGE_B(t + 1, 1);
        __builtin_amdgcn_s_barrier();
        QUAD(1);
        if (more) waitv<LA + LB>();
        __builtin_amdgcn_s_barrier();
    }

    const int er = bm * BM + wr * (BM / 2) + ((lane >> 4) << 2);
    const int ec = bn * BN + wc * (BN / 4) + l15;
    #pragma unroll
    for (int n = 0; n < FN; n++) {
        const int col = ec + n * 16;
        const float bv = (EPI == 3) ? 0.f : bias[col];
        #pragma unroll
        for (int m = 0; m < FM; m++) {
            #pragma unroll
            for (int i = 0; i < 4; i++) {
                const float v = acc[m][n][i] + bv;
                const size_t off = (size_t)(er + m * 16 + i) * N + col;
                if constexpr (EPI == 2) {
                    outb[off] = (bf16)(0.5f * v * (1.f + erff(v * 0.70710678118f)));
                } else {
                    outf[off] = v;
                }
            }
        }
    }
#undef ABASE_
#undef BBASE_
#undef STAGE_A
#undef STAGE_B
#undef LOAD_A
#undef LOAD_B
#undef QUAD
}

// ---------------- orchestration ----------------
extern "C" void kernel_launch(void* const* d_in, const int* in_sizes, int n_in,
                              void* d_out, int out_size, void* d_ws, size_t ws_size,
                              hipStream_t stream)
{
    const int*   ids     = (const int*)  d_in[0];
    const float* tok_emb = (const float*)d_in[1];
    const float* pos_emb = (const float*)d_in[2];
    const float* ln1_s   = (const float*)d_in[3];
    const float* ln1_b   = (const float*)d_in[4];
    const float* qkv_w   = (const float*)d_in[5];
    const float* qkv_b   = (const float*)d_in[6];
    const float* out_w   = (const float*)d_in[7];
    const float* out_b   = (const float*)d_in[8];
    const float* ln2_s   = (const float*)d_in[9];
    const float* ln2_b   = (const float*)d_in[10];
    const float* w1      = (const float*)d_in[11];
    const float* b1      = (const float*)d_in[12];
    const float* w2      = (const float*)d_in[13];
    const float* b2      = (const float*)d_in[14];
    const float* lnf_s   = (const float*)d_in[15];
    const float* lnf_b   = (const float*)d_in[16];
    const float* lm_w    = (const float*)d_in[17];

    char* ws = (char*)d_ws;
    float* x    = (float*)ws;  ws += (size_t)2048 * 1024 * 4;
    bf16*  h    = (bf16*)ws;   ws += (size_t)2048 * 1024 * 2;
    bf16*  qkvb = (bf16*)ws;   ws += (size_t)2048 * 3072 * 2;
    bf16*  attno= (bf16*)ws;   ws += (size_t)2048 * 1024 * 2;
    bf16*  ff   = (bf16*)ws;   ws += (size_t)2048 * 4096 * 2;
    bf16*  wTq  = (bf16*)ws;   ws += (size_t)3072 * 1024 * 2;
    bf16*  wTo  = (bf16*)ws;   ws += (size_t)1024 * 1024 * 2;
    bf16*  wT1  = (bf16*)ws;   ws += (size_t)4096 * 1024 * 2;
    bf16*  wT2  = (bf16*)ws;   ws += (size_t)1024 * 4096 * 2;
    bf16*  wTlm = (bf16*)ws;   ws += (size_t)32000 * 1024 * 2;

    embed_kernel<<<2048, 256, 0, stream>>>(ids, tok_emb, pos_emb, x);

    for (int l = 0; l < 6; l++) {
        // ln1 + wcvt(qkv_w): 2048 + 48*16=768 blocks
        fused_ln_wcvt<<<2048 + 768, 256, 0, stream>>>(
            x, ln1_s + l*1024, ln1_b + l*1024, h,
            qkv_w + (size_t)l*1024*3072, wTq, 1024, 3072, 768,
            nullptr, nullptr, 0, 0);
        gemm_kernel<128,128,0,1><<<16*24, 256, 0, stream>>>(h, wTq, qkv_b + l*3072, nullptr, qkvb, nullptr, 3072, 1024);
        // attn + wcvt(out_w): 512 + 16*16=256 blocks
        fused_attn_wcvt<<<512 + 256, 256, 0, stream>>>(
            qkvb, attno, out_w + (size_t)l*1024*1024, wTo, 1024, 1024);
        gemm_kernel<128,64,1,1><<<16*16, 256, 0, stream>>>(attno, wTo, out_b + l*1024, x, nullptr, nullptr, 1024, 1024);
        // ln2 + wcvt(w1) + wcvt(w2): 2048 + 64*16=1024 + 16*64=1024 blocks
        fused_ln_wcvt<<<2048 + 1024 + 1024, 256, 0, stream>>>(
            x, ln2_s + l*1024, ln2_b + l*1024, h,
            w1 + (size_t)l*1024*4096, wT1, 1024, 4096, 1024,
            w2 + (size_t)l*4096*1024, wT2, 4096, 1024);
        gemm256_kernel<128,256,2><<<256, 512, 98304, stream>>>(h, wT1, b1 + l*4096, ff, nullptr, 4096, 1024);
        // mlp2: split-K=2, atomic residual add
        gemm_kernel<128,64,1,2><<<16*16*2, 256, 0, stream>>>(ff, wT2, b2 + l*1024, x, nullptr, nullptr, 1024, 4096);
    }
    // lnf + wcvt(lm_w): 2048 + 500*16=8000 blocks
    fused_ln_wcvt<<<2048 + 8000, 256, 0, stream>>>(
        x, lnf_s, lnf_b, h,
        lm_w, wTlm, 1024, 32000, 8000,
        nullptr, nullptr, 0, 0);
    gemm256_kernel<256,256,3><<<8*125, 512, 131072, stream>>>(h, wTlm, nullptr, nullptr, (float*)d_out, 32000, 1024);
}

// Round 7
// 1427.556 us; speedup vs baseline: 1.4330x; 1.0245x over previous
//
#include <hip/hip_runtime.h>
#include <hip/hip_bf16.h>
#include <cstdint>
#include <cstddef>

typedef __bf16 bf16;
typedef __attribute__((ext_vector_type(8))) __bf16 bf16x8;
typedef __attribute__((ext_vector_type(4))) __bf16 bf16x4;
typedef __attribute__((ext_vector_type(4))) float f32x4;

__device__ __forceinline__ f32x4 mfma16(bf16x8 a, bf16x8 b, f32x4 c) {
    return __builtin_amdgcn_mfma_f32_16x16x32_bf16(a, b, c, 0, 0, 0);
}

__device__ __forceinline__ void async_copy16(const void* g, void* l) {
    __builtin_amdgcn_global_load_lds((const __attribute__((address_space(1))) void*)g,
                                     (__attribute__((address_space(3))) void*)l,
                                     16, 0, 0);
}

template<int Ncnt> __device__ __forceinline__ void waitv();
template<> __device__ __forceinline__ void waitv<0>() { asm volatile("s_waitcnt vmcnt(0)" ::: "memory"); }
template<> __device__ __forceinline__ void waitv<2>() { asm volatile("s_waitcnt vmcnt(2)" ::: "memory"); }
template<> __device__ __forceinline__ void waitv<3>() { asm volatile("s_waitcnt vmcnt(3)" ::: "memory"); }
template<> __device__ __forceinline__ void waitv<4>() { asm volatile("s_waitcnt vmcnt(4)" ::: "memory"); }

// ---------------- embedding ----------------
__global__ __launch_bounds__(256)
void embed_kernel(const int* __restrict__ ids, const float* __restrict__ te,
                  const float* __restrict__ pe, float* __restrict__ x)
{
    const int row = blockIdx.x;
    const int s = row & 1023;
    const int id = ids[row];
    const f32x4* a = (const f32x4*)(te + (size_t)id * 1024);
    const f32x4* b = (const f32x4*)(pe + (size_t)s * 1024);
    f32x4* o = (f32x4*)(x + (size_t)row * 1024);
    o[threadIdx.x] = a[threadIdx.x] + b[threadIdx.x];
}

// ---------------- device bodies ----------------
__device__ __forceinline__ void ln_body(const float* __restrict__ x, const float* __restrict__ sc,
                                        const float* __restrict__ bi, bf16* __restrict__ out,
                                        int row, int t, float* red)
{
    const f32x4 v = ((const f32x4*)(x + (size_t)row * 1024))[t];
    float s = v[0] + v[1] + v[2] + v[3];
    float q = v[0]*v[0] + v[1]*v[1] + v[2]*v[2] + v[3]*v[3];
    #pragma unroll
    for (int o = 1; o < 64; o <<= 1) { s += __shfl_xor(s, o); q += __shfl_xor(q, o); }
    const int wv = t >> 6, lane = t & 63;
    if (lane == 0) { red[wv] = s; red[4 + wv] = q; }
    __syncthreads();
    s = red[0] + red[1] + red[2] + red[3];
    q = red[4] + red[5] + red[6] + red[7];
    const float mean = s * (1.f / 1024.f);
    const float var  = q * (1.f / 1024.f) - mean * mean;
    const float rstd = rsqrtf(var + 1e-5f);
    const f32x4 scv = ((const f32x4*)sc)[t];
    const f32x4 biv = ((const f32x4*)bi)[t];
    bf16x4 o4;
    #pragma unroll
    for (int j = 0; j < 4; j++) o4[j] = (bf16)((v[j] - mean) * rstd * scv[j] + biv[j]);
    *(bf16x4*)(out + (size_t)row * 1024 + t * 4) = o4;
}

__device__ __forceinline__ void wcvt_body(const float* __restrict__ W, bf16* __restrict__ BT,
                                          int K, int N, int bid, int tidx, float (*tile)[65])
{
    const int nx = N >> 6;
    const int n0 = (bid % nx) << 6, k0 = (bid / nx) << 6;
    const int tx = tidx & 15, ty = tidx >> 4;
    #pragma unroll
    for (int r = 0; r < 4; r++) {
        const f32x4 v = *(const f32x4*)&W[(size_t)(k0 + ty + r*16) * N + n0 + tx*4];
        tile[ty + r*16][tx*4 + 0] = v[0];
        tile[ty + r*16][tx*4 + 1] = v[1];
        tile[ty + r*16][tx*4 + 2] = v[2];
        tile[ty + r*16][tx*4 + 3] = v[3];
    }
    __syncthreads();
    #pragma unroll
    for (int r = 0; r < 4; r++) {
        const int n = ty + r*16;
        bf16x4 o;
        #pragma unroll
        for (int j = 0; j < 4; j++) o[j] = (bf16)tile[tx*4 + j][n];
        *(bf16x4*)&BT[(size_t)(n0 + n) * K + k0 + tx*4] = o;
    }
}

// ---------------- fused LN + up to two weight-converts ----------------
__global__ __launch_bounds__(256)
void fused_ln_wcvt(const float* __restrict__ x, const float* __restrict__ sc,
                   const float* __restrict__ bi, bf16* __restrict__ out,
                   const float* __restrict__ W1, bf16* __restrict__ BT1, int K1, int N1, int nb1,
                   const float* __restrict__ W2, bf16* __restrict__ BT2, int K2, int N2)
{
    __shared__ float tile[64][65];
    __shared__ float red[8];
    const int bid = blockIdx.x, t = threadIdx.x;
    if (bid < 2048) {
        ln_body(x, sc, bi, out, bid, t, red);
    } else {
        const int wb = bid - 2048;
        if (wb < nb1) wcvt_body(W1, BT1, K1, N1, wb, t, tile);
        else          wcvt_body(W2, BT2, K2, N2, wb - nb1, t, tile);
    }
}

// ---------------- fused attention + weight-convert ----------------
__global__ __launch_bounds__(256)
void fused_attn_wcvt(const bf16* __restrict__ qkv, bf16* __restrict__ attno,
                     const float* __restrict__ W, bf16* __restrict__ BT, int K, int N)
{
    __shared__ __align__(16) bf16 Ksh[128 * 64];   // [key][d], chunk-XOR swizzled
    __shared__ __align__(16) bf16 Vt[64][136];     // V^T, padded
    __shared__ __align__(16) bf16 Plds[4][16][40];
    __shared__ float tile[64][65];

    const int bid = blockIdx.x, tid = threadIdx.x;
    if (bid >= 512) {
        wcvt_body(W, BT, K, N, bid - 512, tid, tile);
        return;
    }
    const int b = (bid & 31) >> 4, h = bid & 15;
    const int qb = bid >> 5;
    const int lane = tid & 63, wave = tid >> 6;
    const bf16* base = qkv + (size_t)b * 1024 * 3072;
    const int qrow0 = qb * 64 + wave * 16;

    bf16x8 aQ[2];
    {
        const int qr = qrow0 + (lane & 15);
        const bf16* qp = base + (size_t)qr * 3072 + h * 64 + ((lane >> 4) << 3);
        aQ[0] = *(const bf16x8*)qp;
        aQ[1] = *(const bf16x8*)(qp + 32);
    }
    float m_i[4] = {-1e30f, -1e30f, -1e30f, -1e30f};
    float l_i[4] = {0.f, 0.f, 0.f, 0.f};
    f32x4 acc[4];
    #pragma unroll
    for (int nb = 0; nb < 4; nb++) acc[nb] = f32x4{0.f, 0.f, 0.f, 0.f};

    const int swzA = (((lane >> 4)     ^ (lane & 7)) << 3);
    const int swzB = (((4 + (lane >> 4)) ^ (lane & 7)) << 3);

    for (int ck = 0; ck < 8; ck++) {
        __syncthreads();
        #pragma unroll
        for (int p = 0; p < 4; p++) {
            const int c = p * 256 + tid;
            const int rw = c >> 3;
            const int kc = (c & 7) ^ (rw & 7);
            async_copy16(base + (size_t)(ck*128 + rw) * 3072 + 1024 + h*64 + kc*8, &Ksh[c * 8]);
        }
        #pragma unroll
        for (int p = 0; p < 4; p++) {
            const int idx = p * 256 + tid;
            const int keyl = idx >> 3, dc = idx & 7;
            const bf16x8 v = *(const bf16x8*)&base[(size_t)(ck*128 + keyl) * 3072 + 2048 + h*64 + dc*8];
            #pragma unroll
            for (int e = 0; e < 8; e++) Vt[dc*8 + e][keyl] = v[e];
        }
        __syncthreads();
        for (int kk = 0; kk < 4; kk++) {
            f32x4 s0, s1;
            {
                const int kr0 = (kk*32 + (lane & 15)) * 64;
                const int kr1 = kr0 + 16*64;
                f32x4 z{0.f, 0.f, 0.f, 0.f};
                z = mfma16(aQ[0], *(const bf16x8*)&Ksh[kr0 + swzA], z);
                z = mfma16(aQ[1], *(const bf16x8*)&Ksh[kr0 + swzB], z);
                s0 = z;
                f32x4 z2{0.f, 0.f, 0.f, 0.f};
                z2 = mfma16(aQ[0], *(const bf16x8*)&Ksh[kr1 + swzA], z2);
                z2 = mfma16(aQ[1], *(const bf16x8*)&Ksh[kr1 + swzB], z2);
                s1 = z2;
            }
            float c[4];
            #pragma unroll
            for (int i = 0; i < 4; i++) {
                const float sa = s0[i] * 0.125f, sb = s1[i] * 0.125f;
                float t = fmaxf(sa, sb);
                #pragma unroll
                for (int o = 1; o < 16; o <<= 1) t = fmaxf(t, __shfl_xor(t, o));
                const float mnew = fmaxf(m_i[i], t);
                c[i] = __expf(m_i[i] - mnew);
                const float p0 = __expf(sa - mnew), p1 = __expf(sb - mnew);
                float rs = p0 + p1;
                #pragma unroll
                for (int o = 1; o < 16; o <<= 1) rs += __shfl_xor(rs, o);
                l_i[i] = l_i[i] * c[i] + rs;
                m_i[i] = mnew;
                const int pr = ((lane >> 4) << 2) + i;
                Plds[wave][pr][lane & 15]        = (bf16)p0;
                Plds[wave][pr][16 + (lane & 15)] = (bf16)p1;
            }
            #pragma unroll
            for (int nb = 0; nb < 4; nb++) {
                f32x4 a = acc[nb];
                a[0] *= c[0]; a[1] *= c[1]; a[2] *= c[2]; a[3] *= c[3];
                acc[nb] = a;
            }
            const bf16x8 aP = *(const bf16x8*)&Plds[wave][lane & 15][(lane >> 4) << 3];
            #pragma unroll
            for (int nb = 0; nb < 4; nb++) {
                const bf16x8 bV = *(const bf16x8*)&Vt[nb*16 + (lane & 15)][kk*32 + ((lane >> 4) << 3)];
                acc[nb] = mfma16(aP, bV, acc[nb]);
            }
        }
    }
    #pragma unroll
    for (int nb = 0; nb < 4; nb++) {
        #pragma unroll
        for (int i = 0; i < 4; i++) {
            const int row = qrow0 + ((lane >> 4) << 2) + i;
            const float o = acc[nb][i] / l_i[i];
            attno[(size_t)(b*1024 + row) * 1024 + h*64 + nb*16 + (lane & 15)] = (bf16)o;
        }
    }
}

// ---------------- 128-tile GEMM (2-barrier), optional split-K ----------------
template<int BM, int BN, int EPI, int KSPLIT>
__global__ __launch_bounds__(256)
void gemm_kernel(const bf16* __restrict__ A, const bf16* __restrict__ BT,
                 const float* __restrict__ bias, float* __restrict__ resid,
                 bf16* __restrict__ outb, float* __restrict__ outf,
                 int N, int K)
{
    constexpr int MT = 2048 / BM;
    constexpr int WM = BM / 2, WN = BN / 2;
    constexpr int FM = WM / 16, FN = WN / 16;
    constexpr int CA = BM / 32, CB = BN / 32;
    __shared__ __align__(16) bf16 Asmem[BM * 64];
    __shared__ __align__(16) bf16 Bsmem[BN * 64];

    const int nwg = gridDim.x;
    const int q = nwg >> 3, rr = nwg & 7;
    const int xcd = blockIdx.x & 7, ix = blockIdx.x >> 3;
    const int nid = (xcd < rr ? xcd * (q + 1) : rr * (q + 1) + (xcd - rr) * q) + ix;
    const int tiles = nwg / KSPLIT;
    const int ks = nid / tiles;
    const int tile = nid % tiles;
    const int bm = tile % MT, bn = tile / MT;

    const int tid = threadIdx.x;
    const int lane = tid & 63, wave = tid >> 6;
    const int wr = wave >> 1, wc = wave & 1;
    f32x4 acc[FM][FN];
    #pragma unroll
    for (int m = 0; m < FM; m++)
        #pragma unroll
        for (int n = 0; n < FN; n++) acc[m][n] = f32x4{0.f, 0.f, 0.f, 0.f};

    const bf16* Abase = A  + (size_t)bm * BM * K;
    const bf16* Bbase = BT + (size_t)bn * BN * K;
    const int K64 = K >> 6;
    const int ktlo = ks * (K64 / KSPLIT), kthi = ktlo + (K64 / KSPLIT);
    for (int kt = ktlo; kt < kthi; kt++) {
        __syncthreads();
        #pragma unroll
        for (int p = 0; p < CA; p++) {
            const int idx = p * 256 + tid;
            const int r = idx >> 3, c = (idx & 7) << 3;
            async_copy16(Abase + (size_t)r * K + kt * 64 + c, Asmem + idx * 8);
        }
        #pragma unroll
        for (int p = 0; p < CB; p++) {
            const int idx = p * 256 + tid;
            const int r = idx >> 3, c = (idx & 7) << 3;
            async_copy16(Bbase + (size_t)r * K + kt * 64 + c, Bsmem + idx * 8);
        }
        __syncthreads();
        #pragma unroll
        for (int kss = 0; kss < 2; kss++) {
            bf16x8 af[FM], bfv[FN];
            const int ko = kss * 32 + ((lane >> 4) << 3);
            const int ar = wr * WM + (lane & 15);
            const int br = wc * WN + (lane & 15);
            #pragma unroll
            for (int m = 0; m < FM; m++) af[m]  = *(const bf16x8*)&Asmem[(ar + m*16) * 64 + ko];
            #pragma unroll
            for (int n = 0; n < FN; n++) bfv[n] = *(const bf16x8*)&Bsmem[(br + n*16) * 64 + ko];
            #pragma unroll
            for (int m = 0; m < FM; m++)
                #pragma unroll
                for (int n = 0; n < FN; n++)
                    acc[m][n] = mfma16(af[m], bfv[n], acc[m][n]);
        }
    }
    const int r0 = bm * BM + wr * WM + ((lane >> 4) << 2);
    const int c0 = bn * BN + wc * WN + (lane & 15);
    #pragma unroll
    for (int n = 0; n < FN; n++) {
        const int col = c0 + n * 16;
        const float bv = (EPI == 3) ? 0.f : ((KSPLIT > 1 && ks != 0) ? 0.f : bias[col]);
        #pragma unroll
        for (int m = 0; m < FM; m++) {
            const int row = r0 + m * 16;
            const f32x4 a = acc[m][n];
            #pragma unroll
            for (int i = 0; i < 4; i++) {
                const float v = a[i] + bv;
                const size_t off = (size_t)(row + i) * N + col;
                if constexpr (EPI == 0) outb[off] = (bf16)v;
                else if constexpr (EPI == 1) {
                    if constexpr (KSPLIT > 1) atomicAdd(&resid[off], v);
                    else resid[off] += v;
                }
                else if constexpr (EPI == 2) {
                    const float g = 0.5f * v * (1.f + erff(v * 0.70710678118f));
                    outb[off] = (bf16)g;
                } else outf[off] = v;
            }
        }
    }
}

// ---------------- 8-phase GEMM (T3+T4): counted vmcnt, never 0 mid-loop ----------------
// EPI: 0 bias->bf16 ; 1 bias+residual-add f32 (atomic if KSPLIT>1) ; 2 bias+gelu->bf16 ; 3 f32
template<int BM, int BN, int EPI, int KSPLIT>
__global__ __launch_bounds__(512, 2)
void gemm256_kernel(const bf16* __restrict__ A, const bf16* __restrict__ BT,
                    const float* __restrict__ bias, float* __restrict__ resid,
                    bf16* __restrict__ outb, float* __restrict__ outf,
                    int N, int K)
{
    constexpr int MT = 2048 / BM;
    constexpr int FM = BM / 32;
    constexpr int FN = BN / 64;
    constexpr int HM = FM / 2;
    constexpr int LA = BM / 128, LB = BN / 128;
    constexpr int ASUB = BM * 32;
    constexpr int BSUB = BN * 32;
    extern __shared__ __align__(16) char smem_raw[];
    bf16* smem = (bf16*)smem_raw;

    const int nwg = gridDim.x;
    const int q = nwg >> 3, rr = nwg & 7;
    const int xcd = blockIdx.x & 7, ix = blockIdx.x >> 3;
    const int nid = (xcd < rr ? xcd * (q + 1) : rr * (q + 1) + (xcd - rr) * q) + ix;
    const int tiles = nwg / KSPLIT;
    const int ks = nid / tiles;
    const int tile = nid % tiles;
    const int bm = tile % MT, bn = tile / MT;

    const int tid = threadIdx.x, lane = tid & 63, wave = tid >> 6;
    const int wr = wave >> 2, wc = wave & 3;

    f32x4 acc[FM][FN];
    #pragma unroll
    for (int m = 0; m < FM; m++)
        #pragma unroll
        for (int n = 0; n < FN; n++) acc[m][n] = f32x4{0.f, 0.f, 0.f, 0.f};

    const bf16* Abase = A  + (size_t)bm * BM * K;
    const bf16* Bbase = BT + (size_t)bn * BN * K;
    const int Ts = (K >> 6) / KSPLIT;
    const int t0 = ks * Ts;

    const int l15 = lane & 15;
    const int swz = (((lane >> 4) ^ ((l15 >> 1) & 3)) << 3);
    const int arow0 = wr * (BM / 2) + l15;
    const int brow0 = wc * (BN / 4) + l15;

#define ABASE_(p_, ks_) (((p_)*2 + (ks_)) * ASUB)
#define BBASE_(p_, ks_) (4*ASUB + ((p_)*2 + (ks_)) * BSUB)
#define STAGE_A(p_, kt_, ks_) { _Pragma("unroll") for (int i = 0; i < LA; i++) { \
    const int c = tid + i * 512; const int rw = c >> 2; \
    const int kc = (c & 3) ^ ((rw >> 1) & 3); \
    async_copy16(Abase + (size_t)rw * K + (kt_)*64 + (ks_)*32 + kc*8, \
                 &smem[ABASE_(p_, ks_) + c*8]); } }
#define STAGE_B(p_, kt_, ks_) { _Pragma("unroll") for (int i = 0; i < LB; i++) { \
    const int c = tid + i * 512; const int rw = c >> 2; \
    const int kc = (c & 3) ^ ((rw >> 1) & 3); \
    async_copy16(Bbase + (size_t)rw * K + (kt_)*64 + (ks_)*32 + kc*8, \
                 &smem[BBASE_(p_, ks_) + c*8]); } }
#define LOAD_B(p_, ks_) { _Pragma("unroll") for (int n = 0; n < FN; n++) \
    bfv[n] = *(const bf16x8*)&smem[BBASE_(p_, ks_) + (brow0 + n*16)*32 + swz]; }
#define LOAD_A(p_, ks_, mg) { _Pragma("unroll") for (int m = 0; m < HM; m++) \
    af[m] = *(const bf16x8*)&smem[ABASE_(p_, ks_) + (arow0 + ((mg)*HM + m)*16)*32 + swz]; }
#define QUAD(mg) { __builtin_amdgcn_s_setprio(1); \
    _Pragma("unroll") for (int m = 0; m < HM; m++) \
      _Pragma("unroll") for (int n = 0; n < FN; n++) \
        acc[(mg)*HM + m][n] = mfma16(af[m], bfv[n], acc[(mg)*HM + m][n]); \
    __builtin_amdgcn_s_setprio(0); }

    STAGE_A(0, t0, 0); STAGE_B(0, t0, 0); STAGE_A(0, t0, 1); STAGE_B(0, t0, 1);
    waitv<LA + LB>();
    __builtin_amdgcn_s_barrier();

    for (int tl = 0; tl < Ts; tl++) {
        const int b = tl & 1;
        const int kt1 = t0 + tl + 1;
        const bool more = (tl + 1) < Ts;
        bf16x8 af[HM], bfv[FN];
        LOAD_B(b, 0); LOAD_A(b, 0, 0);
        if (more) STAGE_A(b ^ 1, kt1, 0);
        __builtin_amdgcn_s_barrier();
        QUAD(0);
        __builtin_amdgcn_s_barrier();
        LOAD_A(b, 0, 1);
        if (more) STAGE_B(b ^ 1, kt1, 0);
        __builtin_amdgcn_s_barrier();
        QUAD(1);
        if (more) waitv<LA + LB>(); else waitv<0>();
        __builtin_amdgcn_s_barrier();
        LOAD_B(b, 1); LOAD_A(b, 1, 0);
        if (more) STAGE_A(b ^ 1, kt1, 1);
        __builtin_amdgcn_s_barrier();
        QUAD(0);
        __builtin_amdgcn_s_barrier();
        LOAD_A(b, 1, 1);
        if (more) STAGE_B(b ^ 1, kt1, 1);
        __builtin_amdgcn_s_barrier();
        QUAD(1);
        if (more) waitv<LA + LB>();
        __builtin_amdgcn_s_barrier();
    }

    const int er = bm * BM + wr * (BM / 2) + ((lane >> 4) << 2);
    const int ec = bn * BN + wc * (BN / 4) + l15;
    #pragma unroll
    for (int n = 0; n < FN; n++) {
        const int col = ec + n * 16;
        const float bv = (EPI == 3) ? 0.f : ((KSPLIT > 1 && ks != 0) ? 0.f : bias[col]);
        #pragma unroll
        for (int m = 0; m < FM; m++) {
            #pragma unroll
            for (int i = 0; i < 4; i++) {
                const float v = acc[m][n][i] + bv;
                const size_t off = (size_t)(er + m * 16 + i) * N + col;
                if constexpr (EPI == 0) outb[off] = (bf16)v;
                else if constexpr (EPI == 1) {
                    if constexpr (KSPLIT > 1) atomicAdd(&resid[off], v);
                    else resid[off] += v;
                }
                else if constexpr (EPI == 2) {
                    outb[off] = (bf16)(0.5f * v * (1.f + erff(v * 0.70710678118f)));
                } else {
                    outf[off] = v;
                }
            }
        }
    }
#undef ABASE_
#undef BBASE_
#undef STAGE_A
#undef STAGE_B
#undef LOAD_A
#undef LOAD_B
#undef QUAD
}

// ---------------- orchestration ----------------
extern "C" void kernel_launch(void* const* d_in, const int* in_sizes, int n_in,
                              void* d_out, int out_size, void* d_ws, size_t ws_size,
                              hipStream_t stream)
{
    const int*   ids     = (const int*)  d_in[0];
    const float* tok_emb = (const float*)d_in[1];
    const float* pos_emb = (const float*)d_in[2];
    const float* ln1_s   = (const float*)d_in[3];
    const float* ln1_b   = (const float*)d_in[4];
    const float* qkv_w   = (const float*)d_in[5];
    const float* qkv_b   = (const float*)d_in[6];
    const float* out_w   = (const float*)d_in[7];
    const float* out_b   = (const float*)d_in[8];
    const float* ln2_s   = (const float*)d_in[9];
    const float* ln2_b   = (const float*)d_in[10];
    const float* w1      = (const float*)d_in[11];
    const float* b1      = (const float*)d_in[12];
    const float* w2      = (const float*)d_in[13];
    const float* b2      = (const float*)d_in[14];
    const float* lnf_s   = (const float*)d_in[15];
    const float* lnf_b   = (const float*)d_in[16];
    const float* lm_w    = (const float*)d_in[17];

    char* ws = (char*)d_ws;
    float* x    = (float*)ws;  ws += (size_t)2048 * 1024 * 4;
    bf16*  h    = (bf16*)ws;   ws += (size_t)2048 * 1024 * 2;
    bf16*  qkvb = (bf16*)ws;   ws += (size_t)2048 * 3072 * 2;
    bf16*  attno= (bf16*)ws;   ws += (size_t)2048 * 1024 * 2;
    bf16*  ff   = (bf16*)ws;   ws += (size_t)2048 * 4096 * 2;
    bf16*  wTq  = (bf16*)ws;   ws += (size_t)3072 * 1024 * 2;
    bf16*  wTo  = (bf16*)ws;   ws += (size_t)1024 * 1024 * 2;
    bf16*  wT1  = (bf16*)ws;   ws += (size_t)4096 * 1024 * 2;
    bf16*  wT2  = (bf16*)ws;   ws += (size_t)1024 * 4096 * 2;
    bf16*  wTlm = (bf16*)ws;   ws += (size_t)32000 * 1024 * 2;

    embed_kernel<<<2048, 256, 0, stream>>>(ids, tok_emb, pos_emb, x);

    for (int l = 0; l < 6; l++) {
        if (l == 0) {
            // layer 0: ln1 + wcvt(qkv_w) + wcvt(lm_w) — lm_w hoisted off the tail
            fused_ln_wcvt<<<2048 + 768 + 8000, 256, 0, stream>>>(
                x, ln1_s, ln1_b, h,
                qkv_w, wTq, 1024, 3072, 768,
                lm_w, wTlm, 1024, 32000);
        } else {
            fused_ln_wcvt<<<2048 + 768, 256, 0, stream>>>(
                x, ln1_s + l*1024, ln1_b + l*1024, h,
                qkv_w + (size_t)l*1024*3072, wTq, 1024, 3072, 768,
                nullptr, nullptr, 0, 0);
        }
        gemm256_kernel<128,256,0,1><<<192, 512, 98304, stream>>>(h, wTq, qkv_b + l*3072, nullptr, qkvb, nullptr, 3072, 1024);
        fused_attn_wcvt<<<512 + 256, 256, 0, stream>>>(
            qkvb, attno, out_w + (size_t)l*1024*1024, wTo, 1024, 1024);
        // out-proj: split-K=2, atomic residual add (512 blocks of K=512)
        gemm_kernel<128,64,1,2><<<16*16*2, 256, 0, stream>>>(attno, wTo, out_b + l*1024, x, nullptr, nullptr, 1024, 1024);
        fused_ln_wcvt<<<2048 + 1024 + 1024, 256, 0, stream>>>(
            x, ln2_s + l*1024, ln2_b + l*1024, h,
            w1 + (size_t)l*1024*4096, wT1, 1024, 4096, 1024,
            w2 + (size_t)l*4096*1024, wT2, 4096, 1024);
        gemm256_kernel<128,256,2,1><<<256, 512, 98304, stream>>>(h, wT1, b1 + l*4096, nullptr, ff, nullptr, 4096, 1024);
        gemm_kernel<128,64,1,2><<<16*16*2, 256, 0, stream>>>(ff, wT2, b2 + l*1024, x, nullptr, nullptr, 1024, 4096);
    }
    // tail: lnf only (lm_w already converted in layer 0)
    fused_ln_wcvt<<<2048, 256, 0, stream>>>(
        x, lnf_s, lnf_b, h,
        nullptr, nullptr, 0, 0, 0,
        nullptr, nullptr, 0, 0);
    gemm256_kernel<256,256,3,1><<<8*125, 512, 131072, stream>>>(h, wTlm, nullptr, nullptr, nullptr, (float*)d_out, 32000, 1024);
}

// Round 8
// 1377.015 us; speedup vs baseline: 1.4856x; 1.0367x over previous
//
#include <hip/hip_runtime.h>
#include <hip/hip_bf16.h>
#include <cstdint>
#include <cstddef>

typedef __bf16 bf16;
typedef __attribute__((ext_vector_type(8))) __bf16 bf16x8;
typedef __attribute__((ext_vector_type(4))) __bf16 bf16x4;
typedef __attribute__((ext_vector_type(4))) float f32x4;

__device__ __forceinline__ f32x4 mfma16(bf16x8 a, bf16x8 b, f32x4 c) {
    return __builtin_amdgcn_mfma_f32_16x16x32_bf16(a, b, c, 0, 0, 0);
}

__device__ __forceinline__ void async_copy16(const void* g, void* l) {
    __builtin_amdgcn_global_load_lds((const __attribute__((address_space(1))) void*)g,
                                     (__attribute__((address_space(3))) void*)l,
                                     16, 0, 0);
}

template<int Ncnt> __device__ __forceinline__ void waitv();
template<> __device__ __forceinline__ void waitv<0>() { asm volatile("s_waitcnt vmcnt(0)" ::: "memory"); }
template<> __device__ __forceinline__ void waitv<2>() { asm volatile("s_waitcnt vmcnt(2)" ::: "memory"); }
template<> __device__ __forceinline__ void waitv<3>() { asm volatile("s_waitcnt vmcnt(3)" ::: "memory"); }
template<> __device__ __forceinline__ void waitv<4>() { asm volatile("s_waitcnt vmcnt(4)" ::: "memory"); }

// ---------------- embedding ----------------
__global__ __launch_bounds__(256)
void embed_kernel(const int* __restrict__ ids, const float* __restrict__ te,
                  const float* __restrict__ pe, float* __restrict__ x)
{
    const int row = blockIdx.x;
    const int s = row & 1023;
    const int id = ids[row];
    const f32x4* a = (const f32x4*)(te + (size_t)id * 1024);
    const f32x4* b = (const f32x4*)(pe + (size_t)s * 1024);
    f32x4* o = (f32x4*)(x + (size_t)row * 1024);
    o[threadIdx.x] = a[threadIdx.x] + b[threadIdx.x];
}

// ---------------- device bodies ----------------
__device__ __forceinline__ void ln_body(const float* __restrict__ x, const float* __restrict__ sc,
                                        const float* __restrict__ bi, bf16* __restrict__ out,
                                        int row, int t, float* red)
{
    const f32x4 v = ((const f32x4*)(x + (size_t)row * 1024))[t];
    float s = v[0] + v[1] + v[2] + v[3];
    float q = v[0]*v[0] + v[1]*v[1] + v[2]*v[2] + v[3]*v[3];
    #pragma unroll
    for (int o = 1; o < 64; o <<= 1) { s += __shfl_xor(s, o); q += __shfl_xor(q, o); }
    const int wv = t >> 6, lane = t & 63;
    if (lane == 0) { red[wv] = s; red[4 + wv] = q; }
    __syncthreads();
    s = red[0] + red[1] + red[2] + red[3];
    q = red[4] + red[5] + red[6] + red[7];
    const float mean = s * (1.f / 1024.f);
    const float var  = q * (1.f / 1024.f) - mean * mean;
    const float rstd = rsqrtf(var + 1e-5f);
    const f32x4 scv = ((const f32x4*)sc)[t];
    const f32x4 biv = ((const f32x4*)bi)[t];
    bf16x4 o4;
    #pragma unroll
    for (int j = 0; j < 4; j++) o4[j] = (bf16)((v[j] - mean) * rstd * scv[j] + biv[j]);
    *(bf16x4*)(out + (size_t)row * 1024 + t * 4) = o4;
}

__device__ __forceinline__ void wcvt_body(const float* __restrict__ W, bf16* __restrict__ BT,
                                          int K, int N, int bid, int tidx, float (*tile)[65])
{
    const int nx = N >> 6;
    const int n0 = (bid % nx) << 6, k0 = (bid / nx) << 6;
    const int tx = tidx & 15, ty = tidx >> 4;
    #pragma unroll
    for (int r = 0; r < 4; r++) {
        const f32x4 v = *(const f32x4*)&W[(size_t)(k0 + ty + r*16) * N + n0 + tx*4];
        tile[ty + r*16][tx*4 + 0] = v[0];
        tile[ty + r*16][tx*4 + 1] = v[1];
        tile[ty + r*16][tx*4 + 2] = v[2];
        tile[ty + r*16][tx*4 + 3] = v[3];
    }
    __syncthreads();
    #pragma unroll
    for (int r = 0; r < 4; r++) {
        const int n = ty + r*16;
        bf16x4 o;
        #pragma unroll
        for (int j = 0; j < 4; j++) o[j] = (bf16)tile[tx*4 + j][n];
        *(bf16x4*)&BT[(size_t)(n0 + n) * K + k0 + tx*4] = o;
    }
}

// ---------------- fused LN + up to two weight-converts ----------------
__global__ __launch_bounds__(256)
void fused_ln_wcvt(const float* __restrict__ x, const float* __restrict__ sc,
                   const float* __restrict__ bi, bf16* __restrict__ out,
                   const float* __restrict__ W1, bf16* __restrict__ BT1, int K1, int N1, int nb1,
                   const float* __restrict__ W2, bf16* __restrict__ BT2, int K2, int N2)
{
    __shared__ float tile[64][65];
    __shared__ float red[8];
    const int bid = blockIdx.x, t = threadIdx.x;
    if (bid < 2048) {
        ln_body(x, sc, bi, out, bid, t, red);
    } else {
        const int wb = bid - 2048;
        if (wb < nb1) wcvt_body(W1, BT1, K1, N1, wb, t, tile);
        else          wcvt_body(W2, BT2, K2, N2, wb - nb1, t, tile);
    }
}

// ---------------- fused attention + weight-convert ----------------
// Attention: per-128-key-chunk batched online softmax (one reduce pass per chunk).
__global__ __launch_bounds__(256)
void fused_attn_wcvt(const bf16* __restrict__ qkv, bf16* __restrict__ attno,
                     const float* __restrict__ W, bf16* __restrict__ BT, int K, int N)
{
    __shared__ __align__(16) bf16 Ksh[128 * 64];    // [key][d], chunk-XOR swizzled
    __shared__ __align__(16) bf16 Vt[64][136];      // V^T, padded
    __shared__ __align__(16) bf16 Plds[4][16][132]; // per-wave P rows [q][key 0..127]
    __shared__ float tile[64][65];

    const int bid = blockIdx.x, tid = threadIdx.x;
    if (bid >= 512) {
        wcvt_body(W, BT, K, N, bid - 512, tid, tile);
        return;
    }
    const int b = (bid & 31) >> 4, h = bid & 15;
    const int qb = bid >> 5;
    const int lane = tid & 63, wave = tid >> 6;
    const bf16* base = qkv + (size_t)b * 1024 * 3072;
    const int qrow0 = qb * 64 + wave * 16;
    const int l15 = lane & 15;

    bf16x8 aQ[2];
    {
        const int qr = qrow0 + l15;
        const bf16* qp = base + (size_t)qr * 3072 + h * 64 + ((lane >> 4) << 3);
        aQ[0] = *(const bf16x8*)qp;
        aQ[1] = *(const bf16x8*)(qp + 32);
    }
    float m_i[4] = {-1e30f, -1e30f, -1e30f, -1e30f};
    float l_i[4] = {0.f, 0.f, 0.f, 0.f};
    f32x4 acc[4];
    #pragma unroll
    for (int nb = 0; nb < 4; nb++) acc[nb] = f32x4{0.f, 0.f, 0.f, 0.f};

    const int swzA = (((lane >> 4)     ^ (lane & 7)) << 3);
    const int swzB = (((4 + (lane >> 4)) ^ (lane & 7)) << 3);

    for (int ck = 0; ck < 8; ck++) {
        __syncthreads();
        // stage K[128 keys][64 d] via global_load_lds (source chunk pre-swizzled)
        #pragma unroll
        for (int p = 0; p < 4; p++) {
            const int c = p * 256 + tid;
            const int rw = c >> 3;
            const int kc = (c & 7) ^ (rw & 7);
            async_copy16(base + (size_t)(ck*128 + rw) * 3072 + 1024 + h*64 + kc*8, &Ksh[c * 8]);
        }
        // stage Vt[d][key] (manual transpose)
        #pragma unroll
        for (int p = 0; p < 4; p++) {
            const int idx = p * 256 + tid;
            const int keyl = idx >> 3, dc = idx & 7;
            const bf16x8 v = *(const bf16x8*)&base[(size_t)(ck*128 + keyl) * 3072 + 2048 + h*64 + dc*8];
            #pragma unroll
            for (int e = 0; e < 8; e++) Vt[dc*8 + e][keyl] = v[e];
        }
        __syncthreads();

        // ---- QK^T for all 128 keys: 16 MFMAs into sc[8] ----
        f32x4 sc[8];
        #pragma unroll
        for (int kk = 0; kk < 4; kk++) {
            const int kr0 = (kk*32 + l15) * 64;
            const int kr1 = kr0 + 16*64;
            f32x4 z{0.f, 0.f, 0.f, 0.f};
            z = mfma16(aQ[0], *(const bf16x8*)&Ksh[kr0 + swzA], z);
            z = mfma16(aQ[1], *(const bf16x8*)&Ksh[kr0 + swzB], z);
            sc[2*kk] = z;
            f32x4 z2{0.f, 0.f, 0.f, 0.f};
            z2 = mfma16(aQ[0], *(const bf16x8*)&Ksh[kr1 + swzA], z2);
            z2 = mfma16(aQ[1], *(const bf16x8*)&Ksh[kr1 + swzB], z2);
            sc[2*kk+1] = z2;
        }

        // ---- one batched online-softmax pass over 128 keys ----
        float c[4];
        #pragma unroll
        for (int i = 0; i < 4; i++) {
            float t = sc[0][i];
            #pragma unroll
            for (int e = 1; e < 8; e++) t = fmaxf(t, sc[e][i]);
            #pragma unroll
            for (int o = 1; o < 16; o <<= 1) t = fmaxf(t, __shfl_xor(t, o));
            t *= 0.125f;
            const float mnew = fmaxf(m_i[i], t);
            c[i] = __expf(m_i[i] - mnew);
            float p[8];
            float rs = 0.f;
            #pragma unroll
            for (int e = 0; e < 8; e++) {
                p[e] = __expf(fmaf(sc[e][i], 0.125f, -mnew));
                rs += p[e];
            }
            #pragma unroll
            for (int o = 1; o < 16; o <<= 1) rs += __shfl_xor(rs, o);
            l_i[i] = l_i[i] * c[i] + rs;
            m_i[i] = mnew;
            const int pr = ((lane >> 4) << 2) + i;
            #pragma unroll
            for (int e = 0; e < 8; e++)
                Plds[wave][pr][(e >> 1) * 32 + (e & 1) * 16 + l15] = (bf16)p[e];
        }
        #pragma unroll
        for (int nb = 0; nb < 4; nb++) {
            f32x4 a = acc[nb];
            a[0] *= c[0]; a[1] *= c[1]; a[2] *= c[2]; a[3] *= c[3];
            acc[nb] = a;
        }

        // ---- PV over the 4 key sub-blocks ----
        #pragma unroll
        for (int kk = 0; kk < 4; kk++) {
            const bf16x8 aP = *(const bf16x8*)&Plds[wave][l15][kk*32 + ((lane >> 4) << 3)];
            #pragma unroll
            for (int nb = 0; nb < 4; nb++) {
                const bf16x8 bV = *(const bf16x8*)&Vt[nb*16 + l15][kk*32 + ((lane >> 4) << 3)];
                acc[nb] = mfma16(aP, bV, acc[nb]);
            }
        }
    }
    #pragma unroll
    for (int nb = 0; nb < 4; nb++) {
        #pragma unroll
        for (int i = 0; i < 4; i++) {
            const int row = qrow0 + ((lane >> 4) << 2) + i;
            const float o = acc[nb][i] / l_i[i];
            attno[(size_t)(b*1024 + row) * 1024 + h*64 + nb*16 + l15] = (bf16)o;
        }
    }
}

// ---------------- 128-tile GEMM (2-barrier), optional split-K ----------------
template<int BM, int BN, int EPI, int KSPLIT>
__global__ __launch_bounds__(256)
void gemm_kernel(const bf16* __restrict__ A, const bf16* __restrict__ BT,
                 const float* __restrict__ bias, float* __restrict__ resid,
                 bf16* __restrict__ outb, float* __restrict__ outf,
                 int N, int K)
{
    constexpr int MT = 2048 / BM;
    constexpr int WM = BM / 2, WN = BN / 2;
    constexpr int FM = WM / 16, FN = WN / 16;
    constexpr int CA = BM / 32, CB = BN / 32;
    __shared__ __align__(16) bf16 Asmem[BM * 64];
    __shared__ __align__(16) bf16 Bsmem[BN * 64];

    const int nwg = gridDim.x;
    const int q = nwg >> 3, rr = nwg & 7;
    const int xcd = blockIdx.x & 7, ix = blockIdx.x >> 3;
    const int nid = (xcd < rr ? xcd * (q + 1) : rr * (q + 1) + (xcd - rr) * q) + ix;
    const int tiles = nwg / KSPLIT;
    const int ks = nid / tiles;
    const int tile = nid % tiles;
    const int bm = tile % MT, bn = tile / MT;

    const int tid = threadIdx.x;
    const int lane = tid & 63, wave = tid >> 6;
    const int wr = wave >> 1, wc = wave & 1;
    f32x4 acc[FM][FN];
    #pragma unroll
    for (int m = 0; m < FM; m++)
        #pragma unroll
        for (int n = 0; n < FN; n++) acc[m][n] = f32x4{0.f, 0.f, 0.f, 0.f};

    const bf16* Abase = A  + (size_t)bm * BM * K;
    const bf16* Bbase = BT + (size_t)bn * BN * K;
    const int K64 = K >> 6;
    const int ktlo = ks * (K64 / KSPLIT), kthi = ktlo + (K64 / KSPLIT);
    for (int kt = ktlo; kt < kthi; kt++) {
        __syncthreads();
        #pragma unroll
        for (int p = 0; p < CA; p++) {
            const int idx = p * 256 + tid;
            const int r = idx >> 3, c = (idx & 7) << 3;
            async_copy16(Abase + (size_t)r * K + kt * 64 + c, Asmem + idx * 8);
        }
        #pragma unroll
        for (int p = 0; p < CB; p++) {
            const int idx = p * 256 + tid;
            const int r = idx >> 3, c = (idx & 7) << 3;
            async_copy16(Bbase + (size_t)r * K + kt * 64 + c, Bsmem + idx * 8);
        }
        __syncthreads();
        #pragma unroll
        for (int kss = 0; kss < 2; kss++) {
            bf16x8 af[FM], bfv[FN];
            const int ko = kss * 32 + ((lane >> 4) << 3);
            const int ar = wr * WM + (lane & 15);
            const int br = wc * WN + (lane & 15);
            #pragma unroll
            for (int m = 0; m < FM; m++) af[m]  = *(const bf16x8*)&Asmem[(ar + m*16) * 64 + ko];
            #pragma unroll
            for (int n = 0; n < FN; n++) bfv[n] = *(const bf16x8*)&Bsmem[(br + n*16) * 64 + ko];
            #pragma unroll
            for (int m = 0; m < FM; m++)
                #pragma unroll
                for (int n = 0; n < FN; n++)
                    acc[m][n] = mfma16(af[m], bfv[n], acc[m][n]);
        }
    }
    const int r0 = bm * BM + wr * WM + ((lane >> 4) << 2);
    const int c0 = bn * BN + wc * WN + (lane & 15);
    #pragma unroll
    for (int n = 0; n < FN; n++) {
        const int col = c0 + n * 16;
        const float bv = (EPI == 3) ? 0.f : ((KSPLIT > 1 && ks != 0) ? 0.f : bias[col]);
        #pragma unroll
        for (int m = 0; m < FM; m++) {
            const int row = r0 + m * 16;
            const f32x4 a = acc[m][n];
            #pragma unroll
            for (int i = 0; i < 4; i++) {
                const float v = a[i] + bv;
                const size_t off = (size_t)(row + i) * N + col;
                if constexpr (EPI == 0) outb[off] = (bf16)v;
                else if constexpr (EPI == 1) {
                    if constexpr (KSPLIT > 1) atomicAdd(&resid[off], v);
                    else resid[off] += v;
                }
                else if constexpr (EPI == 2) {
                    const float g = 0.5f * v * (1.f + erff(v * 0.70710678118f));
                    outb[off] = (bf16)g;
                } else outf[off] = v;
            }
        }
    }
}

// ---------------- 8-phase GEMM (T3+T4): counted vmcnt, never 0 mid-loop ----------------
// EPI: 0 bias->bf16 ; 1 bias+residual-add f32 (atomic if KSPLIT>1) ; 2 bias+gelu->bf16 ; 3 f32
template<int BM, int BN, int EPI, int KSPLIT>
__global__ __launch_bounds__(512, 2)
void gemm256_kernel(const bf16* __restrict__ A, const bf16* __restrict__ BT,
                    const float* __restrict__ bias, float* __restrict__ resid,
                    bf16* __restrict__ outb, float* __restrict__ outf,
                    int N, int K)
{
    constexpr int MT = 2048 / BM;
    constexpr int FM = BM / 32;
    constexpr int FN = BN / 64;
    constexpr int HM = FM / 2;
    constexpr int LA = BM / 128, LB = BN / 128;
    constexpr int ASUB = BM * 32;
    constexpr int BSUB = BN * 32;
    extern __shared__ __align__(16) char smem_raw[];
    bf16* smem = (bf16*)smem_raw;

    const int nwg = gridDim.x;
    const int q = nwg >> 3, rr = nwg & 7;
    const int xcd = blockIdx.x & 7, ix = blockIdx.x >> 3;
    const int nid = (xcd < rr ? xcd * (q + 1) : rr * (q + 1) + (xcd - rr) * q) + ix;
    const int tiles = nwg / KSPLIT;
    const int ks = nid / tiles;
    const int tile = nid % tiles;
    const int bm = tile % MT, bn = tile / MT;

    const int tid = threadIdx.x, lane = tid & 63, wave = tid >> 6;
    const int wr = wave >> 2, wc = wave & 3;

    f32x4 acc[FM][FN];
    #pragma unroll
    for (int m = 0; m < FM; m++)
        #pragma unroll
        for (int n = 0; n < FN; n++) acc[m][n] = f32x4{0.f, 0.f, 0.f, 0.f};

    const bf16* Abase = A  + (size_t)bm * BM * K;
    const bf16* Bbase = BT + (size_t)bn * BN * K;
    const int Ts = (K >> 6) / KSPLIT;
    const int t0 = ks * Ts;

    const int l15 = lane & 15;
    const int swz = (((lane >> 4) ^ ((l15 >> 1) & 3)) << 3);
    const int arow0 = wr * (BM / 2) + l15;
    const int brow0 = wc * (BN / 4) + l15;

#define ABASE_(p_, ks_) (((p_)*2 + (ks_)) * ASUB)
#define BBASE_(p_, ks_) (4*ASUB + ((p_)*2 + (ks_)) * BSUB)
#define STAGE_A(p_, kt_, ks_) { _Pragma("unroll") for (int i = 0; i < LA; i++) { \
    const int c = tid + i * 512; const int rw = c >> 2; \
    const int kc = (c & 3) ^ ((rw >> 1) & 3); \
    async_copy16(Abase + (size_t)rw * K + (kt_)*64 + (ks_)*32 + kc*8, \
                 &smem[ABASE_(p_, ks_) + c*8]); } }
#define STAGE_B(p_, kt_, ks_) { _Pragma("unroll") for (int i = 0; i < LB; i++) { \
    const int c = tid + i * 512; const int rw = c >> 2; \
    const int kc = (c & 3) ^ ((rw >> 1) & 3); \
    async_copy16(Bbase + (size_t)rw * K + (kt_)*64 + (ks_)*32 + kc*8, \
                 &smem[BBASE_(p_, ks_) + c*8]); } }
#define LOAD_B(p_, ks_) { _Pragma("unroll") for (int n = 0; n < FN; n++) \
    bfv[n] = *(const bf16x8*)&smem[BBASE_(p_, ks_) + (brow0 + n*16)*32 + swz]; }
#define LOAD_A(p_, ks_, mg) { _Pragma("unroll") for (int m = 0; m < HM; m++) \
    af[m] = *(const bf16x8*)&smem[ABASE_(p_, ks_) + (arow0 + ((mg)*HM + m)*16)*32 + swz]; }
#define QUAD(mg) { __builtin_amdgcn_s_setprio(1); \
    _Pragma("unroll") for (int m = 0; m < HM; m++) \
      _Pragma("unroll") for (int n = 0; n < FN; n++) \
        acc[(mg)*HM + m][n] = mfma16(af[m], bfv[n], acc[(mg)*HM + m][n]); \
    __builtin_amdgcn_s_setprio(0); }

    STAGE_A(0, t0, 0); STAGE_B(0, t0, 0); STAGE_A(0, t0, 1); STAGE_B(0, t0, 1);
    waitv<LA + LB>();
    __builtin_amdgcn_s_barrier();

    for (int tl = 0; tl < Ts; tl++) {
        const int b = tl & 1;
        const int kt1 = t0 + tl + 1;
        const bool more = (tl + 1) < Ts;
        bf16x8 af[HM], bfv[FN];
        LOAD_B(b, 0); LOAD_A(b, 0, 0);
        if (more) STAGE_A(b ^ 1, kt1, 0);
        __builtin_amdgcn_s_barrier();
        QUAD(0);
        __builtin_amdgcn_s_barrier();
        LOAD_A(b, 0, 1);
        if (more) STAGE_B(b ^ 1, kt1, 0);
        __builtin_amdgcn_s_barrier();
        QUAD(1);
        if (more) waitv<LA + LB>(); else waitv<0>();
        __builtin_amdgcn_s_barrier();
        LOAD_B(b, 1); LOAD_A(b, 1, 0);
        if (more) STAGE_A(b ^ 1, kt1, 1);
        __builtin_amdgcn_s_barrier();
        QUAD(0);
        __builtin_amdgcn_s_barrier();
        LOAD_A(b, 1, 1);
        if (more) STAGE_B(b ^ 1, kt1, 1);
        __builtin_amdgcn_s_barrier();
        QUAD(1);
        if (more) waitv<LA + LB>();
        __builtin_amdgcn_s_barrier();
    }

    const int er = bm * BM + wr * (BM / 2) + ((lane >> 4) << 2);
    const int ec = bn * BN + wc * (BN / 4) + l15;
    #pragma unroll
    for (int n = 0; n < FN; n++) {
        const int col = ec + n * 16;
        const float bv = (EPI == 3) ? 0.f : ((KSPLIT > 1 && ks != 0) ? 0.f : bias[col]);
        #pragma unroll
        for (int m = 0; m < FM; m++) {
            #pragma unroll
            for (int i = 0; i < 4; i++) {
                const float v = acc[m][n][i] + bv;
                const size_t off = (size_t)(er + m * 16 + i) * N + col;
                if constexpr (EPI == 0) outb[off] = (bf16)v;
                else if constexpr (EPI == 1) {
                    if constexpr (KSPLIT > 1) atomicAdd(&resid[off], v);
                    else resid[off] += v;
                }
                else if constexpr (EPI == 2) {
                    outb[off] = (bf16)(0.5f * v * (1.f + erff(v * 0.70710678118f)));
                } else {
                    outf[off] = v;
                }
            }
        }
    }
#undef ABASE_
#undef BBASE_
#undef STAGE_A
#undef STAGE_B
#undef LOAD_A
#undef LOAD_B
#undef QUAD
}

// ---------------- orchestration ----------------
extern "C" void kernel_launch(void* const* d_in, const int* in_sizes, int n_in,
                              void* d_out, int out_size, void* d_ws, size_t ws_size,
                              hipStream_t stream)
{
    const int*   ids     = (const int*)  d_in[0];
    const float* tok_emb = (const float*)d_in[1];
    const float* pos_emb = (const float*)d_in[2];
    const float* ln1_s   = (const float*)d_in[3];
    const float* ln1_b   = (const float*)d_in[4];
    const float* qkv_w   = (const float*)d_in[5];
    const float* qkv_b   = (const float*)d_in[6];
    const float* out_w   = (const float*)d_in[7];
    const float* out_b   = (const float*)d_in[8];
    const float* ln2_s   = (const float*)d_in[9];
    const float* ln2_b   = (const float*)d_in[10];
    const float* w1      = (const float*)d_in[11];
    const float* b1      = (const float*)d_in[12];
    const float* w2      = (const float*)d_in[13];
    const float* b2      = (const float*)d_in[14];
    const float* lnf_s   = (const float*)d_in[15];
    const float* lnf_b   = (const float*)d_in[16];
    const float* lm_w    = (const float*)d_in[17];

    char* ws = (char*)d_ws;
    float* x    = (float*)ws;  ws += (size_t)2048 * 1024 * 4;
    bf16*  h    = (bf16*)ws;   ws += (size_t)2048 * 1024 * 2;
    bf16*  qkvb = (bf16*)ws;   ws += (size_t)2048 * 3072 * 2;
    bf16*  attno= (bf16*)ws;   ws += (size_t)2048 * 1024 * 2;
    bf16*  ff   = (bf16*)ws;   ws += (size_t)2048 * 4096 * 2;
    bf16*  wTq  = (bf16*)ws;   ws += (size_t)3072 * 1024 * 2;
    bf16*  wTo  = (bf16*)ws;   ws += (size_t)1024 * 1024 * 2;
    bf16*  wT1  = (bf16*)ws;   ws += (size_t)4096 * 1024 * 2;
    bf16*  wT2  = (bf16*)ws;   ws += (size_t)1024 * 4096 * 2;
    bf16*  wTlm = (bf16*)ws;   ws += (size_t)32000 * 1024 * 2;

    embed_kernel<<<2048, 256, 0, stream>>>(ids, tok_emb, pos_emb, x);

    for (int l = 0; l < 6; l++) {
        if (l == 0) {
            fused_ln_wcvt<<<2048 + 768 + 8000, 256, 0, stream>>>(
                x, ln1_s, ln1_b, h,
                qkv_w, wTq, 1024, 3072, 768,
                lm_w, wTlm, 1024, 32000);
        } else {
            fused_ln_wcvt<<<2048 + 768, 256, 0, stream>>>(
                x, ln1_s + l*1024, ln1_b + l*1024, h,
                qkv_w + (size_t)l*1024*3072, wTq, 1024, 3072, 768,
                nullptr, nullptr, 0, 0);
        }
        gemm256_kernel<128,256,0,1><<<192, 512, 98304, stream>>>(h, wTq, qkv_b + l*3072, nullptr, qkvb, nullptr, 3072, 1024);
        fused_attn_wcvt<<<512 + 256, 256, 0, stream>>>(
            qkvb, attno, out_w + (size_t)l*1024*1024, wTo, 1024, 1024);
        // out-proj: gemm256 KSPLIT=4 (256 blocks, K=256 each), atomic residual add
        gemm256_kernel<128,256,1,4><<<256, 512, 98304, stream>>>(attno, wTo, out_b + l*1024, x, nullptr, nullptr, 1024, 1024);
        fused_ln_wcvt<<<2048 + 1024 + 1024, 256, 0, stream>>>(
            x, ln2_s + l*1024, ln2_b + l*1024, h,
            w1 + (size_t)l*1024*4096, wT1, 1024, 4096, 1024,
            w2 + (size_t)l*4096*1024, wT2, 4096, 1024);
        gemm256_kernel<128,256,2,1><<<256, 512, 98304, stream>>>(h, wT1, b1 + l*4096, nullptr, ff, nullptr, 4096, 1024);
        // mlp2: gemm256 KSPLIT=4 (256 blocks, K=1024 each), atomic residual add
        gemm256_kernel<128,256,1,4><<<256, 512, 98304, stream>>>(ff, wT2, b2 + l*1024, x, nullptr, nullptr, 1024, 4096);
    }
    fused_ln_wcvt<<<2048, 256, 0, stream>>>(
        x, lnf_s, lnf_b, h,
        nullptr, nullptr, 0, 0, 0,
        nullptr, nullptr, 0, 0);
    gemm256_kernel<256,256,3,1><<<8*125, 512, 131072, stream>>>(h, wTlm, nullptr, nullptr, nullptr, (float*)d_out, 32000, 1024);
}

// Round 10
// 1330.073 us; speedup vs baseline: 1.5380x; 1.0353x over previous
//
#include <hip/hip_runtime.h>
#include <hip/hip_bf16.h>
#include <cstdint>
#include <cstddef>

typedef __bf16 bf16;
typedef __attribute__((ext_vector_type(8))) __bf16 bf16x8;
typedef __attribute__((ext_vector_type(4))) __bf16 bf16x4;
typedef __attribute__((ext_vector_type(4))) float f32x4;

__device__ __forceinline__ f32x4 mfma16(bf16x8 a, bf16x8 b, f32x4 c) {
    return __builtin_amdgcn_mfma_f32_16x16x32_bf16(a, b, c, 0, 0, 0);
}

__device__ __forceinline__ void async_copy16(const void* g, void* l) {
    __builtin_amdgcn_global_load_lds((const __attribute__((address_space(1))) void*)g,
                                     (__attribute__((address_space(3))) void*)l,
                                     16, 0, 0);
}

template<int Ncnt> __device__ __forceinline__ void waitv();
template<> __device__ __forceinline__ void waitv<0>() { asm volatile("s_waitcnt vmcnt(0)" ::: "memory"); }
template<> __device__ __forceinline__ void waitv<3>() { asm volatile("s_waitcnt vmcnt(3)" ::: "memory"); }
template<> __device__ __forceinline__ void waitv<4>() { asm volatile("s_waitcnt vmcnt(4)" ::: "memory"); }

// ---------------- embedding ----------------
__global__ __launch_bounds__(256)
void embed_kernel(const int* __restrict__ ids, const float* __restrict__ te,
                  const float* __restrict__ pe, float* __restrict__ x)
{
    const int row = blockIdx.x;
    const int s = row & 1023;
    const int id = ids[row];
    const f32x4* a = (const f32x4*)(te + (size_t)id * 1024);
    const f32x4* b = (const f32x4*)(pe + (size_t)s * 1024);
    f32x4* o = (f32x4*)(x + (size_t)row * 1024);
    o[threadIdx.x] = a[threadIdx.x] + b[threadIdx.x];
}

// ---------------- device bodies ----------------
__device__ __forceinline__ void ln_body(const float* __restrict__ x, const float* __restrict__ sc,
                                        const float* __restrict__ bi, bf16* __restrict__ out,
                                        int row, int t, float* red)
{
    const f32x4 v = ((const f32x4*)(x + (size_t)row * 1024))[t];
    float s = v[0] + v[1] + v[2] + v[3];
    float q = v[0]*v[0] + v[1]*v[1] + v[2]*v[2] + v[3]*v[3];
    #pragma unroll
    for (int o = 1; o < 64; o <<= 1) { s += __shfl_xor(s, o); q += __shfl_xor(q, o); }
    const int wv = t >> 6, lane = t & 63;
    if (lane == 0) { red[wv] = s; red[4 + wv] = q; }
    __syncthreads();
    s = red[0] + red[1] + red[2] + red[3];
    q = red[4] + red[5] + red[6] + red[7];
    const float mean = s * (1.f / 1024.f);
    const float var  = q * (1.f / 1024.f) - mean * mean;
    const float rstd = rsqrtf(var + 1e-5f);
    const f32x4 scv = ((const f32x4*)sc)[t];
    const f32x4 biv = ((const f32x4*)bi)[t];
    bf16x4 o4;
    #pragma unroll
    for (int j = 0; j < 4; j++) o4[j] = (bf16)((v[j] - mean) * rstd * scv[j] + biv[j]);
    *(bf16x4*)(out + (size_t)row * 1024 + t * 4) = o4;
}

__device__ __forceinline__ void wcvt_body(const float* __restrict__ W, bf16* __restrict__ BT,
                                          int K, int N, int bid, int tidx, float (*tile)[65])
{
    const int nx = N >> 6;
    const int n0 = (bid % nx) << 6, k0 = (bid / nx) << 6;
    const int tx = tidx & 15, ty = tidx >> 4;
    #pragma unroll
    for (int r = 0; r < 4; r++) {
        const f32x4 v = *(const f32x4*)&W[(size_t)(k0 + ty + r*16) * N + n0 + tx*4];
        tile[ty + r*16][tx*4 + 0] = v[0];
        tile[ty + r*16][tx*4 + 1] = v[1];
        tile[ty + r*16][tx*4 + 2] = v[2];
        tile[ty + r*16][tx*4 + 3] = v[3];
    }
    __syncthreads();
    #pragma unroll
    for (int r = 0; r < 4; r++) {
        const int n = ty + r*16;
        bf16x4 o;
        #pragma unroll
        for (int j = 0; j < 4; j++) o[j] = (bf16)tile[tx*4 + j][n];
        *(bf16x4*)&BT[(size_t)(n0 + n) * K + k0 + tx*4] = o;
    }
}

// ---------------- front mega-dispatch: ln1(l0) + wcvt qkv(l0) + wcvt lm + wcvt out_w x6 ----
__global__ __launch_bounds__(256)
void front_kernel(const float* __restrict__ x, const float* __restrict__ sc,
                  const float* __restrict__ bi, bf16* __restrict__ out,
                  const float* __restrict__ qkvw0, bf16* __restrict__ wTq,
                  const float* __restrict__ lmw, bf16* __restrict__ wTlm,
                  const float* __restrict__ outw, bf16* __restrict__ wTo_all)
{
    __shared__ float tile[64][65];
    __shared__ float red[8];
    const int bid = blockIdx.x, t = threadIdx.x;
    if (bid < 2048) {
        ln_body(x, sc, bi, out, bid, t, red);
    } else if (bid < 2048 + 768) {
        wcvt_body(qkvw0, wTq, 1024, 3072, bid - 2048, t, tile);
    } else if (bid < 2048 + 768 + 8000) {
        wcvt_body(lmw, wTlm, 1024, 32000, bid - 2816, t, tile);
    } else {
        const int wb = bid - 10816;          // 6 x 256 blocks
        const int l = wb >> 8;
        wcvt_body(outw + (size_t)l * 1024 * 1024, wTo_all + (size_t)l * 1024 * 1024,
                  1024, 1024, wb & 255, t, tile);
    }
}

// ---------------- fused LN + up to two weight-converts (per-layer) ----------------
__global__ __launch_bounds__(256)
void fused_ln_wcvt(const float* __restrict__ x, const float* __restrict__ sc,
                   const float* __restrict__ bi, bf16* __restrict__ out,
                   const float* __restrict__ W1, bf16* __restrict__ BT1, int K1, int N1, int nb1,
                   const float* __restrict__ W2, bf16* __restrict__ BT2, int K2, int N2)
{
    __shared__ float tile[64][65];
    __shared__ float red[8];
    const int bid = blockIdx.x, t = threadIdx.x;
    if (bid < 2048) {
        ln_body(x, sc, bi, out, bid, t, red);
    } else {
        const int wb = bid - 2048;
        if (wb < nb1) wcvt_body(W1, BT1, K1, N1, wb, t, tile);
        else          wcvt_body(W2, BT2, K2, N2, wb - nb1, t, tile);
    }
}

// ---------------- V pre-transpose: vT[b*16+h][d][token] = qkv[b][token][2048+h*64+d] -----
// grid: (32 bh, 8 token-tiles of 128). tile padded to 72 (144 B rows, 16B-aligned).
__global__ __launch_bounds__(256)
void vtrans_kernel(const bf16* __restrict__ qkv, bf16* __restrict__ vT)
{
    __shared__ bf16 tile[128][72];
    const int bh = blockIdx.x;       // b*16+h
    const int tt = blockIdx.y;       // token tile: 0..7
    const int b = bh >> 4, h = bh & 15;
    const bf16* src = qkv + (size_t)b * 1024 * 3072 + 2048 + h * 64;
    const int tid = threadIdx.x;
    #pragma unroll
    for (int i = 0; i < 4; i++) {
        const int c = i * 256 + tid;          // 0..1023
        const int tok = c >> 3, dc = c & 7;
        *(bf16x8*)&tile[tok][dc * 8] = *(const bf16x8*)&src[(size_t)(tt*128 + tok) * 3072 + dc * 8];
    }
    __syncthreads();
    #pragma unroll
    for (int i = 0; i < 4; i++) {
        const int c = i * 256 + tid;
        const int d = c & 63, tc = c >> 6;    // d per lane, token chunk 0..15
        bf16x8 v;
        #pragma unroll
        for (int j = 0; j < 8; j++) v[j] = tile[tc*8 + j][d];
        *(bf16x8*)&vT[((size_t)bh * 64 + d) * 1024 + tt*128 + tc*8] = v;
    }
}

// ---------------- fused attention (pure; K and V^T both via global_load_lds) ----------------
__global__ __launch_bounds__(256)
void attn_kernel(const bf16* __restrict__ qkv, const bf16* __restrict__ vT,
                 bf16* __restrict__ attno)
{
    __shared__ __align__(16) bf16 Ksh[128 * 64];    // [key][d], chunk-XOR swizzled
    __shared__ __align__(16) bf16 Vt[64 * 128];     // [d][key], chunk-XOR swizzled
    __shared__ __align__(16) bf16 Plds[4][16][132];

    const int bid = blockIdx.x, tid = threadIdx.x;
    const int b = (bid & 31) >> 4, h = bid & 15;
    const int qb = bid >> 5;
    const int lane = tid & 63, wave = tid >> 6;
    const bf16* base = qkv + (size_t)b * 1024 * 3072;
    const bf16* vbase = vT + (size_t)(b*16 + h) * 64 * 1024;
    const int qrow0 = qb * 64 + wave * 16;
    const int l15 = lane & 15;

    bf16x8 aQ[2];
    {
        const int qr = qrow0 + l15;
        const bf16* qp = base + (size_t)qr * 3072 + h * 64 + ((lane >> 4) << 3);
        aQ[0] = *(const bf16x8*)qp;
        aQ[1] = *(const bf16x8*)(qp + 32);
    }
    float m_i[4] = {-1e30f, -1e30f, -1e30f, -1e30f};
    float l_i[4] = {0.f, 0.f, 0.f, 0.f};
    f32x4 acc[4];
    #pragma unroll
    for (int nb = 0; nb < 4; nb++) acc[nb] = f32x4{0.f, 0.f, 0.f, 0.f};

    const int swzA = (((lane >> 4)     ^ (lane & 7)) << 3);
    const int swzB = (((4 + (lane >> 4)) ^ (lane & 7)) << 3);

    for (int ck = 0; ck < 8; ck++) {
        __syncthreads();
        // stage K[128 keys][64 d] (8 chunks/row, source chunk pre-swizzled by row&7)
        #pragma unroll
        for (int p = 0; p < 4; p++) {
            const int c = p * 256 + tid;
            const int rw = c >> 3;
            const int kc = (c & 7) ^ (rw & 7);
            async_copy16(base + (size_t)(ck*128 + rw) * 3072 + 1024 + h*64 + kc*8, &Ksh[c * 8]);
        }
        // stage V^T[64 d][128 keys] (16 chunks/row, low-3-bit chunk swizzle by d&7)
        #pragma unroll
        for (int p = 0; p < 4; p++) {
            const int c = p * 256 + tid;
            const int rw = c >> 4;                     // d
            const int kc = (c & 15) ^ (rw & 7);        // involution on low 3 bits
            async_copy16(vbase + (size_t)rw * 1024 + ck*128 + kc*8, &Vt[c * 8]);
        }
        __syncthreads();   // drains vmcnt (global_load_lds) + lgkm

        // ---- QK^T for all 128 keys: 16 MFMAs into sc[8] ----
        f32x4 sc[8];
        #pragma unroll
        for (int kk = 0; kk < 4; kk++) {
            const int kr0 = (kk*32 + l15) * 64;
            const int kr1 = kr0 + 16*64;
            f32x4 z{0.f, 0.f, 0.f, 0.f};
            z = mfma16(aQ[0], *(const bf16x8*)&Ksh[kr0 + swzA], z);
            z = mfma16(aQ[1], *(const bf16x8*)&Ksh[kr0 + swzB], z);
            sc[2*kk] = z;
            f32x4 z2{0.f, 0.f, 0.f, 0.f};
            z2 = mfma16(aQ[0], *(const bf16x8*)&Ksh[kr1 + swzA], z2);
            z2 = mfma16(aQ[1], *(const bf16x8*)&Ksh[kr1 + swzB], z2);
            sc[2*kk+1] = z2;
        }

        // ---- one batched online-softmax pass over 128 keys ----
        float c[4];
        #pragma unroll
        for (int i = 0; i < 4; i++) {
            float t = sc[0][i];
            #pragma unroll
            for (int e = 1; e < 8; e++) t = fmaxf(t, sc[e][i]);
            #pragma unroll
            for (int o = 1; o < 16; o <<= 1) t = fmaxf(t, __shfl_xor(t, o));
            t *= 0.125f;
            const float mnew = fmaxf(m_i[i], t);
            c[i] = __expf(m_i[i] - mnew);
            float p[8];
            float rs = 0.f;
            #pragma unroll
            for (int e = 0; e < 8; e++) {
                p[e] = __expf(fmaf(sc[e][i], 0.125f, -mnew));
                rs += p[e];
            }
            #pragma unroll
            for (int o = 1; o < 16; o <<= 1) rs += __shfl_xor(rs, o);
            l_i[i] = l_i[i] * c[i] + rs;
            m_i[i] = mnew;
            const int pr = ((lane >> 4) << 2) + i;
            #pragma unroll
            for (int e = 0; e < 8; e++)
                Plds[wave][pr][(e >> 1) * 32 + (e & 1) * 16 + l15] = (bf16)p[e];
        }
        #pragma unroll
        for (int nb = 0; nb < 4; nb++) {
            f32x4 a = acc[nb];
            a[0] *= c[0]; a[1] *= c[1]; a[2] *= c[2]; a[3] *= c[3];
            acc[nb] = a;
        }

        // ---- PV over the 4 key sub-blocks (swizzled Vt reads, conflict-free) ----
        #pragma unroll
        for (int kk = 0; kk < 4; kk++) {
            const bf16x8 aP = *(const bf16x8*)&Plds[wave][l15][kk*32 + ((lane >> 4) << 3)];
            #pragma unroll
            for (int nb = 0; nb < 4; nb++) {
                const int r = nb*16 + l15;
                const int chk = (kk*4 + (lane >> 4)) ^ (r & 7);
                const bf16x8 bV = *(const bf16x8*)&Vt[r*128 + chk*8];
                acc[nb] = mfma16(aP, bV, acc[nb]);
            }
        }
    }
    #pragma unroll
    for (int nb = 0; nb < 4; nb++) {
        #pragma unroll
        for (int i = 0; i < 4; i++) {
            const int row = qrow0 + ((lane >> 4) << 2) + i;
            const float o = acc[nb][i] / l_i[i];
            attno[(size_t)(b*1024 + row) * 1024 + h*64 + nb*16 + l15] = (bf16)o;
        }
    }
}

// ---------------- 8-phase GEMM (T3+T4): counted vmcnt, never 0 mid-loop ----------------
// EPI: 0 bias->bf16 ; 1 bias+residual-add f32 (atomic if KSPLIT>1) ; 2 bias+gelu->bf16 ; 3 f32
template<int BM, int BN, int EPI, int KSPLIT>
__global__ __launch_bounds__(512, 2)
void gemm256_kernel(const bf16* __restrict__ A, const bf16* __restrict__ BT,
                    const float* __restrict__ bias, float* __restrict__ resid,
                    bf16* __restrict__ outb, float* __restrict__ outf,
                    int N, int K)
{
    constexpr int MT = 2048 / BM;
    constexpr int FM = BM / 32;
    constexpr int FN = BN / 64;
    constexpr int HM = FM / 2;
    constexpr int LA = BM / 128, LB = BN / 128;
    constexpr int ASUB = BM * 32;
    constexpr int BSUB = BN * 32;
    extern __shared__ __align__(16) char smem_raw[];
    bf16* smem = (bf16*)smem_raw;

    const int nwg = gridDim.x;
    const int q = nwg >> 3, rr = nwg & 7;
    const int xcd = blockIdx.x & 7, ix = blockIdx.x >> 3;
    const int nid = (xcd < rr ? xcd * (q + 1) : rr * (q + 1) + (xcd - rr) * q) + ix;
    const int tiles = nwg / KSPLIT;
    const int ks = nid / tiles;
    const int tile = nid % tiles;
    const int bm = tile % MT, bn = tile / MT;

    const int tid = threadIdx.x, lane = tid & 63, wave = tid >> 6;
    const int wr = wave >> 2, wc = wave & 3;

    f32x4 acc[FM][FN];
    #pragma unroll
    for (int m = 0; m < FM; m++)
        #pragma unroll
        for (int n = 0; n < FN; n++) acc[m][n] = f32x4{0.f, 0.f, 0.f, 0.f};

    const bf16* Abase = A  + (size_t)bm * BM * K;
    const bf16* Bbase = BT + (size_t)bn * BN * K;
    const int Ts = (K >> 6) / KSPLIT;
    const int t0 = ks * Ts;

    const int l15 = lane & 15;
    const int swz = (((lane >> 4) ^ ((l15 >> 1) & 3)) << 3);
    const int arow0 = wr * (BM / 2) + l15;
    const int brow0 = wc * (BN / 4) + l15;

#define ABASE_(p_, ks_) (((p_)*2 + (ks_)) * ASUB)
#define BBASE_(p_, ks_) (4*ASUB + ((p_)*2 + (ks_)) * BSUB)
#define STAGE_A(p_, kt_, ks_) { _Pragma("unroll") for (int i = 0; i < LA; i++) { \
    const int c = tid + i * 512; const int rw = c >> 2; \
    const int kc = (c & 3) ^ ((rw >> 1) & 3); \
    async_copy16(Abase + (size_t)rw * K + (kt_)*64 + (ks_)*32 + kc*8, \
                 &smem[ABASE_(p_, ks_) + c*8]); } }
#define STAGE_B(p_, kt_, ks_) { _Pragma("unroll") for (int i = 0; i < LB; i++) { \
    const int c = tid + i * 512; const int rw = c >> 2; \
    const int kc = (c & 3) ^ ((rw >> 1) & 3); \
    async_copy16(Bbase + (size_t)rw * K + (kt_)*64 + (ks_)*32 + kc*8, \
                 &smem[BBASE_(p_, ks_) + c*8]); } }
#define LOAD_B(p_, ks_) { _Pragma("unroll") for (int n = 0; n < FN; n++) \
    bfv[n] = *(const bf16x8*)&smem[BBASE_(p_, ks_) + (brow0 + n*16)*32 + swz]; }
#define LOAD_A(p_, ks_, mg) { _Pragma("unroll") for (int m = 0; m < HM; m++) \
    af[m] = *(const bf16x8*)&smem[ABASE_(p_, ks_) + (arow0 + ((mg)*HM + m)*16)*32 + swz]; }
#define QUAD(mg) { __builtin_amdgcn_s_setprio(1); \
    _Pragma("unroll") for (int m = 0; m < HM; m++) \
      _Pragma("unroll") for (int n = 0; n < FN; n++) \
        acc[(mg)*HM + m][n] = mfma16(af[m], bfv[n], acc[(mg)*HM + m][n]); \
    __builtin_amdgcn_s_setprio(0); }

    STAGE_A(0, t0, 0); STAGE_B(0, t0, 0); STAGE_A(0, t0, 1); STAGE_B(0, t0, 1);
    waitv<LA + LB>();
    __builtin_amdgcn_s_barrier();

    for (int tl = 0; tl < Ts; tl++) {
        const int b = tl & 1;
        const int kt1 = t0 + tl + 1;
        const bool more = (tl + 1) < Ts;
        bf16x8 af[HM], bfv[FN];
        LOAD_B(b, 0); LOAD_A(b, 0, 0);
        if (more) STAGE_A(b ^ 1, kt1, 0);
        __builtin_amdgcn_s_barrier();
        QUAD(0);
        __builtin_amdgcn_s_barrier();
        LOAD_A(b, 0, 1);
        if (more) STAGE_B(b ^ 1, kt1, 0);
        __builtin_amdgcn_s_barrier();
        QUAD(1);
        if (more) waitv<LA + LB>(); else waitv<0>();
        __builtin_amdgcn_s_barrier();
        LOAD_B(b, 1); LOAD_A(b, 1, 0);
        if (more) STAGE_A(b ^ 1, kt1, 1);
        __builtin_amdgcn_s_barrier();
        QUAD(0);
        __builtin_amdgcn_s_barrier();
        LOAD_A(b, 1, 1);
        if (more) STAGE_B(b ^ 1, kt1, 1);
        __builtin_amdgcn_s_barrier();
        QUAD(1);
        if (more) waitv<LA + LB>();
        __builtin_amdgcn_s_barrier();
    }

    const int er = bm * BM + wr * (BM / 2) + ((lane >> 4) << 2);
    const int ec = bn * BN + wc * (BN / 4) + l15;
    #pragma unroll
    for (int n = 0; n < FN; n++) {
        const int col = ec + n * 16;
        const float bv = (EPI == 3) ? 0.f : ((KSPLIT > 1 && ks != 0) ? 0.f : bias[col]);
        #pragma unroll
        for (int m = 0; m < FM; m++) {
            #pragma unroll
            for (int i = 0; i < 4; i++) {
                const float v = acc[m][n][i] + bv;
                const size_t off = (size_t)(er + m * 16 + i) * N + col;
                if constexpr (EPI == 0) outb[off] = (bf16)v;
                else if constexpr (EPI == 1) {
                    if constexpr (KSPLIT > 1) atomicAdd(&resid[off], v);
                    else resid[off] += v;
                }
                else if constexpr (EPI == 2) {
                    outb[off] = (bf16)(0.5f * v * (1.f + erff(v * 0.70710678118f)));
                } else {
                    outf[off] = v;
                }
            }
        }
    }
#undef ABASE_
#undef BBASE_
#undef STAGE_A
#undef STAGE_B
#undef LOAD_A
#undef LOAD_B
#undef QUAD
}

// ---------------- orchestration ----------------
extern "C" void kernel_launch(void* const* d_in, const int* in_sizes, int n_in,
                              void* d_out, int out_size, void* d_ws, size_t ws_size,
                              hipStream_t stream)
{
    const int*   ids     = (const int*)  d_in[0];
    const float* tok_emb = (const float*)d_in[1];
    const float* pos_emb = (const float*)d_in[2];
    const float* ln1_s   = (const float*)d_in[3];
    const float* ln1_b   = (const float*)d_in[4];
    const float* qkv_w   = (const float*)d_in[5];
    const float* qkv_b   = (const float*)d_in[6];
    const float* out_w   = (const float*)d_in[7];
    const float* out_b   = (const float*)d_in[8];
    const float* ln2_s   = (const float*)d_in[9];
    const float* ln2_b   = (const float*)d_in[10];
    const float* w1      = (const float*)d_in[11];
    const float* b1      = (const float*)d_in[12];
    const float* w2      = (const float*)d_in[13];
    const float* b2      = (const float*)d_in[14];
    const float* lnf_s   = (const float*)d_in[15];
    const float* lnf_b   = (const float*)d_in[16];
    const float* lm_w    = (const float*)d_in[17];

    char* ws = (char*)d_ws;
    float* x    = (float*)ws;  ws += (size_t)2048 * 1024 * 4;
    bf16*  h    = (bf16*)ws;   ws += (size_t)2048 * 1024 * 2;
    bf16*  qkvb = (bf16*)ws;   ws += (size_t)2048 * 3072 * 2;
    bf16*  attno= (bf16*)ws;   ws += (size_t)2048 * 1024 * 2;
    bf16*  vT   = (bf16*)ws;   ws += (size_t)32 * 64 * 1024 * 2;
    bf16*  ff   = (bf16*)ws;   ws += (size_t)2048 * 4096 * 2;
    bf16*  wTq  = (bf16*)ws;   ws += (size_t)3072 * 1024 * 2;
    bf16*  wTo_all = (bf16*)ws; ws += (size_t)6 * 1024 * 1024 * 2;
    bf16*  wT1  = (bf16*)ws;   ws += (size_t)4096 * 1024 * 2;
    bf16*  wT2  = (bf16*)ws;   ws += (size_t)1024 * 4096 * 2;
    bf16*  wTlm = (bf16*)ws;   ws += (size_t)32000 * 1024 * 2;

    embed_kernel<<<2048, 256, 0, stream>>>(ids, tok_emb, pos_emb, x);

    for (int l = 0; l < 6; l++) {
        if (l == 0) {
            front_kernel<<<12352, 256, 0, stream>>>(
                x, ln1_s, ln1_b, h,
                qkv_w, wTq, lm_w, wTlm, out_w, wTo_all);
        } else {
            fused_ln_wcvt<<<2048 + 768, 256, 0, stream>>>(
                x, ln1_s + l*1024, ln1_b + l*1024, h,
                qkv_w + (size_t)l*1024*3072, wTq, 1024, 3072, 768,
                nullptr, nullptr, 0, 0);
        }
        gemm256_kernel<128,256,0,1><<<192, 512, 98304, stream>>>(h, wTq, qkv_b + l*3072, nullptr, qkvb, nullptr, 3072, 1024);
        vtrans_kernel<<<dim3(32, 8), 256, 0, stream>>>(qkvb, vT);
        attn_kernel<<<512, 256, 0, stream>>>(qkvb, vT, attno);
        gemm256_kernel<128,256,1,4><<<256, 512, 98304, stream>>>(attno, wTo_all + (size_t)l*1024*1024, out_b + l*1024, x, nullptr, nullptr, 1024, 1024);
        fused_ln_wcvt<<<2048 + 1024 + 1024, 256, 0, stream>>>(
            x, ln2_s + l*1024, ln2_b + l*1024, h,
            w1 + (size_t)l*1024*4096, wT1, 1024, 4096, 1024,
            w2 + (size_t)l*4096*1024, wT2, 4096, 1024);
        gemm256_kernel<128,256,2,1><<<256, 512, 98304, stream>>>(h, wT1, b1 + l*4096, nullptr, ff, nullptr, 4096, 1024);
        gemm256_kernel<128,256,1,4><<<256, 512, 98304, stream>>>(ff, wT2, b2 + l*1024, x, nullptr, nullptr, 1024, 4096);
    }
    fused_ln_wcvt<<<2048, 256, 0, stream>>>(
        x, lnf_s, lnf_b, h,
        nullptr, nullptr, 0, 0, 0,
        nullptr, nullptr, 0, 0);
    gemm256_kernel<256,256,3,1><<<8*125, 512, 131072, stream>>>(h, wTlm, nullptr, nullptr, nullptr, (float*)d_out, 32000, 1024);
}